// Round 2
// baseline (1915.993 us; speedup 1.0000x reference)
//
#include <hip/hip_runtime.h>
#include <math.h>

// MLA + MoE block for gfx950.
// Pre-routing path (LN1 -> Wdq/Wuq/Wdkv/Wukv GEMMs -> RoPE -> flash attn -> Wo+resid)
// runs in bf16 hi/lo split precision (3-MFMA per product, rel err ~2^-17) so the
// f32 routing top-2 matches the reference bit-for-decision. MoE bulk is plain bf16.
// Workspace ~100 MB with manually-verified buffer overlays.

#define DEV __device__ __forceinline__

typedef __attribute__((ext_vector_type(8))) short short8;
typedef __attribute__((ext_vector_type(8))) __bf16 bf16x8;
typedef __attribute__((ext_vector_type(4))) float floatx4;

DEV short f2bf(float f) {
  union { float f; unsigned u; } v; v.f = f;
  unsigned r = v.u + 0x7fffu + ((v.u >> 16) & 1u);
  return (short)(r >> 16);
}
DEV float bf2f(short s) {
  union { float f; unsigned u; } v; v.u = ((unsigned)(unsigned short)s) << 16;
  return v.f;
}
DEV float gelu_f(float v) { return 0.5f * v * (1.0f + erff(v * 0.70710678118654752f)); }

DEV floatx4 mfma16(short8 a, short8 b, floatx4 c) {
  return __builtin_amdgcn_mfma_f32_16x16x32_bf16(
      __builtin_bit_cast(bf16x8, a), __builtin_bit_cast(bf16x8, b), c, 0, 0, 0);
}
DEV void async16(void* lds_uniform, const void* gptr) {
  __builtin_amdgcn_global_load_lds(
      (const __attribute__((address_space(1))) void*)gptr,
      (__attribute__((address_space(3))) void*)lds_uniform, 16, 0, 0);
}

// ---------------- prep: casts ----------------

__global__ void cast_bf4(const float4* __restrict__ src, short4* __restrict__ dst, long n4) {
  long i = (long)blockIdx.x * blockDim.x + threadIdx.x;
  long stride = (long)gridDim.x * blockDim.x;
  for (; i < n4; i += stride) {
    float4 v = src[i];
    short4 o; o.x = f2bf(v.x); o.y = f2bf(v.y); o.z = f2bf(v.z); o.w = f2bf(v.w);
    dst[i] = o;
  }
}

__global__ void cast_hl4(const float4* __restrict__ src, short4* __restrict__ dhi,
                         short4* __restrict__ dlo, long n4) {
  long i = (long)blockIdx.x * blockDim.x + threadIdx.x;
  long stride = (long)gridDim.x * blockDim.x;
  for (; i < n4; i += stride) {
    float4 v = src[i];
    short4 h, l;
    h.x = f2bf(v.x); l.x = f2bf(v.x - bf2f(h.x));
    h.y = f2bf(v.y); l.y = f2bf(v.y - bf2f(h.y));
    h.z = f2bf(v.z); l.z = f2bf(v.z - bf2f(h.z));
    h.w = f2bf(v.w); l.w = f2bf(v.w - bf2f(h.w));
    dhi[i] = h; dlo[i] = l;
  }
}

// src (K,N) f32 -> dst_hi/lo (Npad,K) bf16 (rows >= N zero)
__launch_bounds__(256)
__global__ void transpose_cast_hl(const float* __restrict__ src, short* __restrict__ dhi,
                                  short* __restrict__ dlo, int K, int N) {
  __shared__ float tile[64][65];
  int k0 = blockIdx.x * 64, n0 = blockIdx.y * 64;
  for (int i = threadIdx.x; i < 4096; i += 256) {
    int r = i >> 6, c = i & 63;
    tile[r][c] = (n0 + c < N) ? src[(size_t)(k0 + r) * N + n0 + c] : 0.f;
  }
  __syncthreads();
  for (int i = threadIdx.x; i < 4096; i += 256) {
    int r = i >> 6, c = i & 63;
    float v = tile[c][r];
    short h = f2bf(v);
    dhi[(size_t)(n0 + r) * K + k0 + c] = h;
    dlo[(size_t)(n0 + r) * K + k0 + c] = f2bf(v - bf2f(h));
  }
}

// ---------------- LayerNorm variants ----------------

__launch_bounds__(256)
__global__ void ln_hl(const float* __restrict__ in, int ldi, int N,
                      const float* __restrict__ w, const float* __restrict__ b,
                      short* __restrict__ ohi, short* __restrict__ olo, int ldo) {
  const int row = blockIdx.x * 4 + (threadIdx.x >> 6);
  const int lane = threadIdx.x & 63;
  const float* r = in + (size_t)row * ldi;
  float s = 0.f, s2 = 0.f;
  for (int i = lane; i < N; i += 64) { float v = r[i]; s += v; s2 += v * v; }
#pragma unroll
  for (int off = 32; off >= 1; off >>= 1) { s += __shfl_xor(s, off); s2 += __shfl_xor(s2, off); }
  float mean = s / N, var = s2 / N - mean * mean;
  float rstd = rsqrtf(var + 1e-5f);
  for (int i = lane; i < N; i += 64) {
    float y = (r[i] - mean) * rstd * w[i];
    if (b) y += b[i];
    short h = f2bf(y);
    ohi[(size_t)row * ldo + i] = h;
    olo[(size_t)row * ldo + i] = f2bf(y - bf2f(h));
  }
}

__launch_bounds__(256)
__global__ void ln_bf_f32(const float* __restrict__ in,
                          const float* __restrict__ w,
                          short* __restrict__ obf, float* __restrict__ of) {
  const int row = blockIdx.x * 4 + (threadIdx.x >> 6);
  const int lane = threadIdx.x & 63;
  const float* r = in + (size_t)row * 768;
  float s = 0.f, s2 = 0.f;
  for (int i = lane; i < 768; i += 64) { float v = r[i]; s += v; s2 += v * v; }
#pragma unroll
  for (int off = 32; off >= 1; off >>= 1) { s += __shfl_xor(s, off); s2 += __shfl_xor(s2, off); }
  float mean = s / 768.f, var = s2 / 768.f - mean * mean;
  float rstd = rsqrtf(var + 1e-5f);
  for (int i = lane; i < 768; i += 64) {
    float y = (r[i] - mean) * rstd * w[i];
    obf[(size_t)row * 768 + i] = f2bf(y);
    of[(size_t)row * 768 + i] = y;
  }
}

// ---------------- split-precision GEMM: C = A*Bt^T (+resid), f32 out ----------------
// A,Bt given as bf16 hi/lo planes. 128x128 tile, 3 MFMAs per (i,j,k).

template<int RESID>
__launch_bounds__(256)
__global__ void gemm3(const short* __restrict__ Ahi, const short* __restrict__ Alo, int lda,
                      const short* __restrict__ Bhi, const short* __restrict__ Blo, int ldb,
                      float* __restrict__ Cf, int ldc, const float* __restrict__ resid,
                      int M, int N, int K) {
  __shared__ __align__(16) short AsH[4096], AsL[4096], BsH[4096], BsL[4096];
  const int tid = threadIdx.x;
  const int m0 = blockIdx.y * 128, n0 = blockIdx.x * 128;
  const int wave = tid >> 6, lane = tid & 63;
  const int wm = (wave >> 1) * 64, wn = (wave & 1) * 64;
  const int lr = lane & 15, lk = (lane >> 4) * 8, rb = (lane >> 4) * 4;
  const floatx4 fz = {0.f, 0.f, 0.f, 0.f};
  floatx4 acc[4][4];
#pragma unroll
  for (int i = 0; i < 4; i++)
#pragma unroll
    for (int j = 0; j < 4; j++) acc[i][j] = fz;
  const size_t rowA = (size_t)(m0 + (tid >> 2)) * lda + (tid & 3) * 8;
  const size_t rowB = (size_t)(n0 + (tid >> 2)) * ldb + (tid & 3) * 8;
  const size_t a64 = (size_t)64 * lda, b64 = (size_t)64 * ldb;
  short* AsHW = AsH + wave * 512; short* AsLW = AsL + wave * 512;
  short* BsHW = BsH + wave * 512; short* BsLW = BsL + wave * 512;
  for (int k0 = 0; k0 < K; k0 += 32) {
    async16(AsHW, Ahi + rowA + k0);        async16(AsHW + 2048, Ahi + rowA + a64 + k0);
    async16(AsLW, Alo + rowA + k0);        async16(AsLW + 2048, Alo + rowA + a64 + k0);
    async16(BsHW, Bhi + rowB + k0);        async16(BsHW + 2048, Bhi + rowB + b64 + k0);
    async16(BsLW, Blo + rowB + k0);        async16(BsLW + 2048, Blo + rowB + b64 + k0);
    __syncthreads();
    short8 ah[4], al[4], bh[4], bl[4];
#pragma unroll
    for (int i = 0; i < 4; i++) {
      ah[i] = *(const short8*)&AsH[(wm + i * 16 + lr) * 32 + lk];
      al[i] = *(const short8*)&AsL[(wm + i * 16 + lr) * 32 + lk];
    }
#pragma unroll
    for (int j = 0; j < 4; j++) {
      bh[j] = *(const short8*)&BsH[(wn + j * 16 + lr) * 32 + lk];
      bl[j] = *(const short8*)&BsL[(wn + j * 16 + lr) * 32 + lk];
    }
#pragma unroll
    for (int i = 0; i < 4; i++)
#pragma unroll
      for (int j = 0; j < 4; j++) {
        acc[i][j] = mfma16(ah[i], bh[j], acc[i][j]);
        acc[i][j] = mfma16(ah[i], bl[j], acc[i][j]);
        acc[i][j] = mfma16(al[i], bh[j], acc[i][j]);
      }
    __syncthreads();
  }
#pragma unroll
  for (int i = 0; i < 4; i++) {
    int row = m0 + wm + i * 16 + rb;
#pragma unroll
    for (int j = 0; j < 4; j++) {
      int col = n0 + wn + j * 16 + lr;
      if (col < N) {
#pragma unroll
        for (int r = 0; r < 4; r++) {
          int rr = row + r;
          if (rr < M) {
            float v = acc[i][j][r];
            if (RESID) v += resid[(size_t)rr * ldc + col];
            Cf[(size_t)rr * ldc + col] = v;
          }
        }
      }
    }
  }
}

// ---------------- plain bf16 GEMM for MoE ----------------

template<int ACT, int BETA, int RESID>
__launch_bounds__(256)
__global__ void gemm1(const short* __restrict__ A, int lda,
                      const short* __restrict__ Bt, int ldb,
                      float* __restrict__ Cf, short* __restrict__ Cb, int ldc,
                      const float* __restrict__ resid,
                      int M, int N, int K) {
  __shared__ __align__(16) short As[4096], Bs[4096];
  const int tid = threadIdx.x;
  const int m0 = blockIdx.y * 128, n0 = blockIdx.x * 128;
  const int wave = tid >> 6, lane = tid & 63;
  const int wm = (wave >> 1) * 64, wn = (wave & 1) * 64;
  const int lr = lane & 15, lk = (lane >> 4) * 8, rb = (lane >> 4) * 4;
  const floatx4 fz = {0.f, 0.f, 0.f, 0.f};
  floatx4 acc[4][4];
#pragma unroll
  for (int i = 0; i < 4; i++)
#pragma unroll
    for (int j = 0; j < 4; j++) acc[i][j] = fz;
  const short* Ag = A + (size_t)(m0 + (tid >> 2)) * lda + (tid & 3) * 8;
  const short* Bg = Bt + (size_t)(n0 + (tid >> 2)) * ldb + (tid & 3) * 8;
  short* AsW = As + wave * 512; short* BsW = Bs + wave * 512;
  const size_t a64 = (size_t)64 * lda, b64 = (size_t)64 * ldb;
  for (int k0 = 0; k0 < K; k0 += 32) {
    async16(AsW, Ag + k0);  async16(AsW + 2048, Ag + a64 + k0);
    async16(BsW, Bg + k0);  async16(BsW + 2048, Bg + b64 + k0);
    __syncthreads();
    short8 af[4], bfr[4];
#pragma unroll
    for (int i = 0; i < 4; i++) af[i] = *(const short8*)&As[(wm + i * 16 + lr) * 32 + lk];
#pragma unroll
    for (int j = 0; j < 4; j++) bfr[j] = *(const short8*)&Bs[(wn + j * 16 + lr) * 32 + lk];
#pragma unroll
    for (int i = 0; i < 4; i++)
#pragma unroll
      for (int j = 0; j < 4; j++) acc[i][j] = mfma16(af[i], bfr[j], acc[i][j]);
    __syncthreads();
  }
#pragma unroll
  for (int i = 0; i < 4; i++) {
    int row = m0 + wm + i * 16 + rb;
#pragma unroll
    for (int j = 0; j < 4; j++) {
      int col = n0 + wn + j * 16 + lr;
      if (col < N) {
#pragma unroll
        for (int r = 0; r < 4; r++) {
          int rr = row + r;
          if (rr < M) {
            float v = acc[i][j][r];
            if (RESID) v += resid[(size_t)rr * ldc + col];
            if (BETA) v += Cf[(size_t)rr * ldc + col];
            if (ACT == 1) v = gelu_f(v);
            if (Cf) Cf[(size_t)rr * ldc + col] = v;
            if (Cb) Cb[(size_t)rr * ldc + col] = f2bf(v);
          }
        }
      }
    }
  }
}

// ---------------- RoPE builders (hi/lo planes) ----------------

__global__ void build_q_hl(const float* __restrict__ Qf, short* __restrict__ qh,
                           short* __restrict__ ql) {
  int id = blockIdx.x * blockDim.x + threadIdx.x;
  if (id >= 4096 * 12) return;
  int token = id / 12, h = id - token * 12;
  int s = token & 1023, b = token >> 10;
  const float* q = Qf + (size_t)token * 768 + h * 64;
  size_t base = ((size_t)(b * 12 + h) * 1024 + s) * 64;
  float vals[64];
#pragma unroll
  for (int d = 0; d < 32; d++) vals[d] = q[d];
#pragma unroll
  for (int i = 0; i < 16; i++) {
    float fi = powf(10000.f, -(float)(2 * i) / 64.f);
    float sn, cs; sincosf((float)s * fi, &sn, &cs);
    vals[32 + i] = q[32 + i] * cs - q[48 + i] * sn;
    vals[48 + i] = q[48 + i] * cs + q[32 + i] * sn;
  }
#pragma unroll
  for (int d = 0; d < 64; d++) {
    short hh = f2bf(vals[d]);
    qh[base + d] = hh;
    ql[base + d] = f2bf(vals[d] - bf2f(hh));
  }
}

__global__ void build_kv_hl(const float* __restrict__ KVf, const float* __restrict__ ckv,
                            short* __restrict__ kh, short* __restrict__ kl,
                            short* __restrict__ vth, short* __restrict__ vtl) {
  int id = blockIdx.x * blockDim.x + threadIdx.x;
  if (id >= 4096 * 12) return;
  int token = id / 12, h = id - token * 12;
  int s = token & 1023, b = token >> 10;
  const float* kv = KVf + (size_t)token * 1152 + h * 96;
  size_t kb = ((size_t)(b * 12 + h) * 1024 + s) * 64;
  float kvals[64];
#pragma unroll
  for (int d = 0; d < 32; d++) kvals[d] = kv[d];
  const float* kr = ckv + (size_t)token * 544 + 512;
#pragma unroll
  for (int i = 0; i < 16; i++) {
    float fi = powf(10000.f, -(float)(2 * i) / 64.f);
    float sn, cs; sincosf((float)s * fi, &sn, &cs);
    kvals[32 + i] = kr[i] * cs - kr[16 + i] * sn;
    kvals[48 + i] = kr[16 + i] * cs + kr[i] * sn;
  }
#pragma unroll
  for (int d = 0; d < 64; d++) {
    short hh = f2bf(kvals[d]);
    kh[kb + d] = hh;
    kl[kb + d] = f2bf(kvals[d] - bf2f(hh));
  }
  size_t vb = (size_t)(b * 12 + h) * 65536 + s;
#pragma unroll
  for (int d = 0; d < 64; d++) {
    float v = kv[32 + d];
    short hh = f2bf(v);
    vth[vb + (size_t)d * 1024] = hh;
    vtl[vb + (size_t)d * 1024] = f2bf(v - bf2f(hh));
  }
}

// ---------------- flash attention, split precision ----------------

__launch_bounds__(256)
__global__ void attn3(const short* __restrict__ qbh, const short* __restrict__ qbl,
                      const short* __restrict__ kbh, const short* __restrict__ kbl,
                      const short* __restrict__ vth, const short* __restrict__ vtl,
                      short* __restrict__ obh, short* __restrict__ obl) {
  const int qt = blockIdx.x, bh = blockIdx.y;
  const int b = bh / 12, h = bh - b * 12;
  const short* Qh = qbh + (size_t)bh * 65536;
  const short* Ql = qbl + (size_t)bh * 65536;
  const short* Kh = kbh + (size_t)bh * 65536;
  const short* Kl = kbl + (size_t)bh * 65536;
  const short* Vh = vth + (size_t)bh * 65536;
  const short* Vl = vtl + (size_t)bh * 65536;
  __shared__ __align__(16) short KsH[4096], KsL[4096], VsH[4096], VsL[4096], PsH[4096], PsL[4096];
  const int tid = threadIdx.x, wave = tid >> 6, lane = tid & 63;
  const int lr = lane & 15, q4 = lane >> 4, lk = (lane >> 4) * 8;
  const int qrow0 = qt * 64 + wave * 16;
  short8 qfh[2], qfl[2];
  qfh[0] = *(const short8*)&Qh[(size_t)(qrow0 + lr) * 64 + lk];
  qfh[1] = *(const short8*)&Qh[(size_t)(qrow0 + lr) * 64 + 32 + lk];
  qfl[0] = *(const short8*)&Ql[(size_t)(qrow0 + lr) * 64 + lk];
  qfl[1] = *(const short8*)&Ql[(size_t)(qrow0 + lr) * 64 + 32 + lk];
  const floatx4 fz = {0.f, 0.f, 0.f, 0.f};
  floatx4 oacc[4];
#pragma unroll
  for (int t = 0; t < 4; t++) oacc[t] = fz;
  float m_i[4], l_i[4];
#pragma unroll
  for (int r = 0; r < 4; r++) { m_i[r] = -__builtin_inff(); l_i[r] = 0.f; }
  const int srow = tid >> 3, soff = (tid & 7) * 8;
  short* KsHW = KsH + wave * 512; short* KsLW = KsL + wave * 512;
  short* VsHW = VsH + wave * 512; short* VsLW = VsL + wave * 512;
  short* myPh = PsH + wave * 1024; short* myPl = PsL + wave * 1024;
  for (int kt = 0; kt <= qt; kt++) {
    __syncthreads();
    size_t krow = (size_t)(kt * 64 + srow) * 64 + soff;
    size_t vrow = (size_t)srow * 1024 + kt * 64 + soff;
    async16(KsHW, Kh + krow);        async16(KsHW + 2048, Kh + krow + 32 * 64);
    async16(KsLW, Kl + krow);        async16(KsLW + 2048, Kl + krow + 32 * 64);
    async16(VsHW, Vh + vrow);        async16(VsHW + 2048, Vh + vrow + 32 * 1024);
    async16(VsLW, Vl + vrow);        async16(VsLW + 2048, Vl + vrow + 32 * 1024);
    __syncthreads();
    floatx4 sacc[4];
#pragma unroll
    for (int j = 0; j < 4; j++) sacc[j] = fz;
#pragma unroll
    for (int j = 0; j < 4; j++) {
      short8 kh0 = *(const short8*)&KsH[(j * 16 + lr) * 64 + lk];
      short8 kh1 = *(const short8*)&KsH[(j * 16 + lr) * 64 + 32 + lk];
      short8 kl0 = *(const short8*)&KsL[(j * 16 + lr) * 64 + lk];
      short8 kl1 = *(const short8*)&KsL[(j * 16 + lr) * 64 + 32 + lk];
      sacc[j] = mfma16(qfh[0], kh0, sacc[j]);
      sacc[j] = mfma16(qfh[1], kh1, sacc[j]);
      sacc[j] = mfma16(qfh[0], kl0, sacc[j]);
      sacc[j] = mfma16(qfh[1], kl1, sacc[j]);
      sacc[j] = mfma16(qfl[0], kh0, sacc[j]);
      sacc[j] = mfma16(qfl[1], kh1, sacc[j]);
    }
    float pv[4][4], mrow[4];
#pragma unroll
    for (int r = 0; r < 4; r++) mrow[r] = -__builtin_inff();
    const bool diag = (kt == qt);
#pragma unroll
    for (int j = 0; j < 4; j++)
#pragma unroll
      for (int r = 0; r < 4; r++) {
        float v = sacc[j][r] * 0.125f;
        if (diag) {
          int qg = qrow0 + q4 * 4 + r;
          int kg = kt * 64 + j * 16 + lr;
          if (kg > qg) v = -__builtin_inff();
        }
        pv[j][r] = v;
        mrow[r] = fmaxf(mrow[r], v);
      }
#pragma unroll
    for (int r = 0; r < 4; r++)
#pragma unroll
      for (int off = 1; off < 16; off <<= 1) mrow[r] = fmaxf(mrow[r], __shfl_xor(mrow[r], off));
    float alpha[4], rsum[4];
#pragma unroll
    for (int r = 0; r < 4; r++) {
      float nm = fmaxf(m_i[r], mrow[r]);
      alpha[r] = __expf(m_i[r] - nm);
      m_i[r] = nm; rsum[r] = 0.f;
    }
#pragma unroll
    for (int j = 0; j < 4; j++)
#pragma unroll
      for (int r = 0; r < 4; r++) {
        float pe = __expf(pv[j][r] - m_i[r]);
        pv[j][r] = pe; rsum[r] += pe;
      }
#pragma unroll
    for (int r = 0; r < 4; r++) {
#pragma unroll
      for (int off = 1; off < 16; off <<= 1) rsum[r] += __shfl_xor(rsum[r], off);
      l_i[r] = l_i[r] * alpha[r] + rsum[r];
    }
#pragma unroll
    for (int t = 0; t < 4; t++)
#pragma unroll
      for (int r = 0; r < 4; r++) oacc[t][r] *= alpha[r];
#pragma unroll
    for (int j = 0; j < 4; j++)
#pragma unroll
      for (int r = 0; r < 4; r++) {
        float p = pv[j][r];
        short hh = f2bf(p);
        myPh[(q4 * 4 + r) * 64 + j * 16 + lr] = hh;
        myPl[(q4 * 4 + r) * 64 + j * 16 + lr] = f2bf(p - bf2f(hh));
      }
    __asm__ volatile("s_waitcnt lgkmcnt(0)" ::: "memory");
#pragma unroll
    for (int c = 0; c < 2; c++) {
      short8 ph = *(const short8*)&myPh[lr * 64 + c * 32 + lk];
      short8 pl = *(const short8*)&myPl[lr * 64 + c * 32 + lk];
#pragma unroll
      for (int t = 0; t < 4; t++) {
        short8 vh = *(const short8*)&VsH[(t * 16 + lr) * 64 + c * 32 + lk];
        short8 vl = *(const short8*)&VsL[(t * 16 + lr) * 64 + c * 32 + lk];
        oacc[t] = mfma16(ph, vh, oacc[t]);
        oacc[t] = mfma16(ph, vl, oacc[t]);
        oacc[t] = mfma16(pl, vh, oacc[t]);
      }
    }
  }
#pragma unroll
  for (int t = 0; t < 4; t++)
#pragma unroll
    for (int r = 0; r < 4; r++) {
      int s = qrow0 + q4 * 4 + r;
      int token = b * 1024 + s;
      float ov = oacc[t][r] / l_i[r];
      short hh = f2bf(ov);
      size_t idx = (size_t)token * 768 + h * 64 + t * 16 + lr;
      obh[idx] = hh;
      obl[idx] = f2bf(ov - bf2f(hh));
    }
}

// ---------------- routing (f32 exact) ----------------

__launch_bounds__(256)
__global__ void route_kernel(const float* __restrict__ h2f, const float* __restrict__ cent,
                             const float* __restrict__ rbias,
                             int* __restrict__ counts, int* __restrict__ lists,
                             float* __restrict__ gates) {
  const int token = blockIdx.x * 4 + (threadIdx.x >> 6);
  const int lane = threadIdx.x & 63;
  const float* hv = h2f + (size_t)token * 768;
  float raw[8];
#pragma unroll
  for (int e = 0; e < 8; e++) {
    const float* cv = cent + e * 768;
    float p = 0.f;
    for (int i = lane; i < 768; i += 64) p += hv[i] * cv[i];
#pragma unroll
    for (int off = 32; off >= 1; off >>= 1) p += __shfl_xor(p, off);
    raw[e] = p;
  }
  if (lane == 0) {
    float b0 = -__builtin_inff(); int i1 = 0;
#pragma unroll
    for (int e = 0; e < 8; e++) { float be = raw[e] + rbias[e]; if (be > b0) { b0 = be; i1 = e; } }
    float b1 = -__builtin_inff(); int i2 = 0;
#pragma unroll
    for (int e = 0; e < 8; e++) {
      if (e == i1) continue;
      float be = raw[e] + rbias[e];
      if (be > b1) { b1 = be; i2 = e; }
    }
    float w1 = 1.f / (1.f + expf(-raw[i1]));
    float w2 = 1.f / (1.f + expf(-raw[i2]));
    float wsum = w1 + w2 + 1e-9f;
    w1 /= wsum; w2 /= wsum;
    int p1 = atomicAdd(&counts[i1], 1);
    lists[i1 * 4096 + p1] = token;
    gates[token] = w1;
    int p2 = atomicAdd(&counts[i2], 1);
    lists[i2 * 4096 + p2] = 4096 + token;
    gates[4096 + token] = w2;
  }
}

// ---------------- per-expert grouped GEMMs ----------------

__launch_bounds__(256)
__global__ void expert_fc(const short* __restrict__ h2bf, const short* __restrict__ wfc,
                          const int* __restrict__ elist, const int* __restrict__ ecnt,
                          short* __restrict__ act) {
  const int cnt = *ecnt;
  const int m0 = blockIdx.y * 128;
  if (m0 >= cnt) return;
  const int n0 = blockIdx.x * 128;
  __shared__ __align__(16) short As[4096], Bs[4096];
  __shared__ int slots[128];
  const int tid = threadIdx.x;
  if (tid < 128) slots[tid] = elist[m0 + tid];
  __syncthreads();
  const int tokA0 = slots[tid >> 2] & 4095;
  const int tokA1 = slots[64 + (tid >> 2)] & 4095;
  const int wave = tid >> 6, lane = tid & 63;
  const int wm = (wave >> 1) * 64, wn = (wave & 1) * 64;
  const int lr = lane & 15, lk = (lane >> 4) * 8, rb = (lane >> 4) * 4;
  const floatx4 fz = {0.f, 0.f, 0.f, 0.f};
  floatx4 acc[4][4];
#pragma unroll
  for (int i = 0; i < 4; i++)
#pragma unroll
    for (int j = 0; j < 4; j++) acc[i][j] = fz;
  const short* Ag0 = h2bf + (size_t)tokA0 * 768 + (tid & 3) * 8;
  const short* Ag1 = h2bf + (size_t)tokA1 * 768 + (tid & 3) * 8;
  const short* Bg = wfc + (size_t)(n0 + (tid >> 2)) * 768 + (tid & 3) * 8;
  short* AsW = As + wave * 512; short* BsW = Bs + wave * 512;
  for (int k0 = 0; k0 < 768; k0 += 32) {
    async16(AsW, Ag0 + k0);  async16(AsW + 2048, Ag1 + k0);
    async16(BsW, Bg + k0);   async16(BsW + 2048, Bg + (size_t)64 * 768 + k0);
    __syncthreads();
    short8 af[4], bfr[4];
#pragma unroll
    for (int i = 0; i < 4; i++) af[i] = *(const short8*)&As[(wm + i * 16 + lr) * 32 + lk];
#pragma unroll
    for (int j = 0; j < 4; j++) bfr[j] = *(const short8*)&Bs[(wn + j * 16 + lr) * 32 + lk];
#pragma unroll
    for (int i = 0; i < 4; i++)
#pragma unroll
      for (int j = 0; j < 4; j++) acc[i][j] = mfma16(af[i], bfr[j], acc[i][j]);
    __syncthreads();
  }
#pragma unroll
  for (int i = 0; i < 4; i++) {
    int lrow = wm + i * 16 + rb;
#pragma unroll
    for (int j = 0; j < 4; j++) {
      int col = n0 + wn + j * 16 + lr;
#pragma unroll
      for (int r = 0; r < 4; r++) {
        if (m0 + lrow + r < cnt)
          act[(size_t)(m0 + lrow + r) * 3072 + col] = f2bf(gelu_f(acc[i][j][r]));
      }
    }
  }
}

__launch_bounds__(256)
__global__ void expert_proj(const short* __restrict__ act, const short* __restrict__ wproj,
                            const int* __restrict__ elist, const int* __restrict__ ecnt,
                            const float* __restrict__ gates, float* __restrict__ out) {
  const int cnt = *ecnt;
  const int m0 = blockIdx.y * 128;
  if (m0 >= cnt) return;
  const int n0 = blockIdx.x * 128;
  __shared__ __align__(16) short As[4096], Bs[4096];
  __shared__ int slots[128];
  const int tid = threadIdx.x;
  if (tid < 128) slots[tid] = elist[m0 + tid];
  __syncthreads();
  const int wave = tid >> 6, lane = tid & 63;
  const int wm = (wave >> 1) * 64, wn = (wave & 1) * 64;
  const int lr = lane & 15, lk = (lane >> 4) * 8, rb = (lane >> 4) * 4;
  const floatx4 fz = {0.f, 0.f, 0.f, 0.f};
  floatx4 acc[4][4];
#pragma unroll
  for (int i = 0; i < 4; i++)
#pragma unroll
    for (int j = 0; j < 4; j++) acc[i][j] = fz;
  const short* Ag = act + (size_t)(m0 + (tid >> 2)) * 3072 + (tid & 3) * 8;
  const short* Bg = wproj + (size_t)(n0 + (tid >> 2)) * 3072 + (tid & 3) * 8;
  short* AsW = As + wave * 512; short* BsW = Bs + wave * 512;
  for (int k0 = 0; k0 < 3072; k0 += 32) {
    async16(AsW, Ag + k0);  async16(AsW + 2048, Ag + (size_t)64 * 3072 + k0);
    async16(BsW, Bg + k0);  async16(BsW + 2048, Bg + (size_t)64 * 3072 + k0);
    __syncthreads();
    short8 af[4], bfr[4];
#pragma unroll
    for (int i = 0; i < 4; i++) af[i] = *(const short8*)&As[(wm + i * 16 + lr) * 32 + lk];
#pragma unroll
    for (int j = 0; j < 4; j++) bfr[j] = *(const short8*)&Bs[(wn + j * 16 + lr) * 32 + lk];
#pragma unroll
    for (int i = 0; i < 4; i++)
#pragma unroll
      for (int j = 0; j < 4; j++) acc[i][j] = mfma16(af[i], bfr[j], acc[i][j]);
    __syncthreads();
  }
#pragma unroll
  for (int i = 0; i < 4; i++) {
    int lrow = wm + i * 16 + rb;
#pragma unroll
    for (int j = 0; j < 4; j++) {
      int col = n0 + wn + j * 16 + lr;
#pragma unroll
      for (int r = 0; r < 4; r++) {
        if (m0 + lrow + r < cnt) {
          int slot = slots[lrow + r];
          int token = slot & 4095;
          atomicAdd(&out[(size_t)token * 768 + col], gates[slot] * acc[i][j][r]);
        }
      }
    }
  }
}

__global__ void bad_kernel(float* out) { out[threadIdx.x] = 1e30f; }

// ---------------- launch ----------------

extern "C" void kernel_launch(void* const* d_in, const int* in_sizes, int n_in,
                              void* d_out, int out_size, void* d_ws, size_t ws_size,
                              hipStream_t stream) {
  const float* x = (const float*)d_in[0];
  const float* ln1_w = (const float*)d_in[1];
  const float* ln2_w = (const float*)d_in[2];
  const float* W_dq = (const float*)d_in[3];
  const float* W_uq = (const float*)d_in[4];
  const float* q_ln_w = (const float*)d_in[5];
  const float* q_ln_b = (const float*)d_in[6];
  const float* W_dkv = (const float*)d_in[7];
  const float* W_ukv = (const float*)d_in[8];
  const float* kv_ln_w = (const float*)d_in[9];
  const float* kv_ln_b = (const float*)d_in[10];
  const float* W_o = (const float*)d_in[11];
  const float* s_fc = (const float*)d_in[12];
  const float* s_proj = (const float*)d_in[13];
  const float* e_fc = (const float*)d_in[14];
  const float* e_proj = (const float*)d_in[15];
  const float* cent = (const float*)d_in[16];
  const float* rbias = (const float*)d_in[17];
  float* out = (float*)d_out;

  char* base = (char*)d_ws;
  size_t off = 0;
  auto take = [&](size_t bytes) -> char* {
    char* r = base + off;
    off = (off + bytes + 255) & ~(size_t)255;
    return r;
  };
  // persistent
  short* WdqH  = (short*)take(589824);  short* WdqL  = (short*)take(589824);
  short* WuqH  = (short*)take(589824);  short* WuqL  = (short*)take(589824);
  short* WdkvH = (short*)take(983040);  short* WdkvL = (short*)take(983040);
  short* WukvH = (short*)take(1179648); short* WukvL = (short*)take(1179648);
  short* WoH   = (short*)take(1179648); short* WoL   = (short*)take(1179648);
  float* x2    = (float*)take(12582912);
  float* gates = (float*)take(32768);
  int*   counts= (int*)take(32);
  int*   lists = (int*)take(131072);
  // pool with overlays
  const size_t PLANE = 6291456;  // 4096*768*2 bytes
  char* pA = take(2 * PLANE);
  char* pB = take(2 * PLANE);
  char* pC = take(2 * PLANE);
  char* pD = take(2 * PLANE);
  char* pE = take(18874368);
  char* pF = take(8912896);
  size_t used = off;
  if (used > ws_size) { bad_kernel<<<1, 256, 0, stream>>>(out); return; }

  short* hH    = (short*)pA;             short* hL    = (short*)(pA + PLANE);
  short* kvlH  = (short*)pA;             short* kvlL  = (short*)(pA + 4194304);
  short* kbH   = (short*)pA;             short* kbL   = (short*)(pA + PLANE);
  float* cqpre = (float*)pB;
  short* cqH   = (short*)(pB + PLANE);   short* cqL   = (short*)(pB + PLANE + 3145728);
  short* vtH   = (short*)pB;             short* vtL   = (short*)(pB + PLANE);
  short* wbufB = (short*)pB;
  float* Qf    = (float*)pC;
  short* obH   = (short*)pC;             short* obL   = (short*)(pC + PLANE);
  short* h2bf  = (short*)pC;             short* wbufA = (short*)(pC + PLANE);
  short* qbH   = (short*)pD;             short* qbL   = (short*)(pD + PLANE);
  float* h2f   = (float*)pD;
  float* KVf   = (float*)pE;
  short* actb  = (short*)pE;             // 25.2 MB spans pE+pF
  float* ckv   = (float*)pF;

  hipMemsetAsync(counts, 0, (size_t)((char*)lists - (char*)counts) + 131072, stream);

  // weight prep (hi/lo)
  cast_hl4<<<576, 256, 0, stream>>>((const float4*)W_o, (short4*)WoH, (short4*)WoL, 147456);
  transpose_cast_hl<<<dim3(12, 6), 256, 0, stream>>>(W_dq, WdqH, WdqL, 768, 384);
  transpose_cast_hl<<<dim3(6, 12), 256, 0, stream>>>(W_uq, WuqH, WuqL, 384, 768);
  transpose_cast_hl<<<dim3(12, 10), 256, 0, stream>>>(W_dkv, WdkvH, WdkvL, 768, 544);
  transpose_cast_hl<<<dim3(8, 18), 256, 0, stream>>>(W_ukv, WukvH, WukvL, 512, 1152);

  // phase A: pre-routing path in split precision
  ln_hl<<<1024, 256, 0, stream>>>(x, 768, 768, ln1_w, nullptr, hH, hL, 768);
  gemm3<0><<<dim3(3, 32), 256, 0, stream>>>(hH, hL, 768, WdqH, WdqL, 768, cqpre, 384, nullptr, 4096, 384, 768);
  ln_hl<<<1024, 256, 0, stream>>>(cqpre, 384, 384, q_ln_w, q_ln_b, cqH, cqL, 384);
  gemm3<0><<<dim3(6, 32), 256, 0, stream>>>(cqH, cqL, 384, WuqH, WuqL, 384, Qf, 768, nullptr, 4096, 768, 384);
  build_q_hl<<<192, 256, 0, stream>>>(Qf, qbH, qbL);
  gemm3<0><<<dim3(5, 32), 256, 0, stream>>>(hH, hL, 768, WdkvH, WdkvL, 768, ckv, 544, nullptr, 4096, 544, 768);
  ln_hl<<<1024, 256, 0, stream>>>(ckv, 544, 512, kv_ln_w, kv_ln_b, kvlH, kvlL, 512);
  gemm3<0><<<dim3(9, 32), 256, 0, stream>>>(kvlH, kvlL, 512, WukvH, WukvL, 512, KVf, 1152, nullptr, 4096, 1152, 512);
  build_kv_hl<<<192, 256, 0, stream>>>(KVf, ckv, kbH, kbL, vtH, vtL);
  attn3<<<dim3(16, 48), 256, 0, stream>>>(qbH, qbL, kbH, kbL, vtH, vtL, obH, obL);
  gemm3<1><<<dim3(6, 32), 256, 0, stream>>>(obH, obL, 768, WoH, WoL, 768, x2, 768, x, 4096, 768, 768);

  // phase B: LN2, routing, MoE (plain bf16)
  ln_bf_f32<<<1024, 256, 0, stream>>>(x2, ln2_w, h2bf, h2f);
  route_kernel<<<1024, 256, 0, stream>>>(h2f, cent, rbias, counts, lists, gates);

  // shared expert 0: out = x2 + proj(gelu(fc(h2)))
  cast_bf4<<<1024, 256, 0, stream>>>((const float4*)s_fc, (short4*)wbufA, 589824);
  gemm1<1, 0, 0><<<dim3(24, 32), 256, 0, stream>>>(h2bf, 768, wbufA, 768, nullptr, actb, 3072, nullptr, 4096, 3072, 768);
  cast_bf4<<<1024, 256, 0, stream>>>((const float4*)s_proj, (short4*)wbufB, 589824);
  gemm1<0, 0, 1><<<dim3(6, 32), 256, 0, stream>>>(actb, 3072, wbufB, 3072, out, nullptr, 768, x2, 4096, 768, 3072);
  // shared expert 1: out += proj(gelu(fc(h2)))
  cast_bf4<<<1024, 256, 0, stream>>>((const float4*)(s_fc + (size_t)3072 * 768), (short4*)wbufA, 589824);
  gemm1<1, 0, 0><<<dim3(24, 32), 256, 0, stream>>>(h2bf, 768, wbufA, 768, nullptr, actb, 3072, nullptr, 4096, 3072, 768);
  cast_bf4<<<1024, 256, 0, stream>>>((const float4*)(s_proj + (size_t)768 * 3072), (short4*)wbufB, 589824);
  gemm1<0, 1, 0><<<dim3(6, 32), 256, 0, stream>>>(actb, 3072, wbufB, 3072, out, nullptr, 768, nullptr, 4096, 768, 3072);

  // routed experts, one at a time (act buffer reused; scatter via atomicAdd into out)
  for (int e = 0; e < 8; e++) {
    cast_bf4<<<1024, 256, 0, stream>>>((const float4*)(e_fc + (size_t)e * 3072 * 768), (short4*)wbufA, 589824);
    expert_fc<<<dim3(24, 32), 256, 0, stream>>>(h2bf, wbufA, lists + e * 4096, counts + e, actb);
    cast_bf4<<<1024, 256, 0, stream>>>((const float4*)(e_proj + (size_t)e * 768 * 3072), (short4*)wbufB, 589824);
    expert_proj<<<dim3(6, 32), 256, 0, stream>>>(actb, wbufB, lists + e * 4096, counts + e, gates, out);
  }
}

// Round 3
// 1772.171 us; speedup vs baseline: 1.0812x; 1.0812x over previous
//
#include <hip/hip_runtime.h>
#include <math.h>

// MLA + MoE block for gfx950.
// Pre-routing path in bf16 hi/lo split precision (3-MFMA, rel err ~2^-17) so f32
// routing top-2 matches the reference decisions. MoE bulk in plain bf16.
// R2: atomic-free routing (score + ballot compaction), LDS-transposed V build,
// merged per-expert weight casts.

#define DEV __device__ __forceinline__

typedef __attribute__((ext_vector_type(8))) short short8;
typedef __attribute__((ext_vector_type(8))) __bf16 bf16x8;
typedef __attribute__((ext_vector_type(4))) float floatx4;

DEV short f2bf(float f) {
  union { float f; unsigned u; } v; v.f = f;
  unsigned r = v.u + 0x7fffu + ((v.u >> 16) & 1u);
  return (short)(r >> 16);
}
DEV float bf2f(short s) {
  union { float f; unsigned u; } v; v.u = ((unsigned)(unsigned short)s) << 16;
  return v.f;
}
DEV float gelu_f(float v) { return 0.5f * v * (1.0f + erff(v * 0.70710678118654752f)); }

DEV floatx4 mfma16(short8 a, short8 b, floatx4 c) {
  return __builtin_amdgcn_mfma_f32_16x16x32_bf16(
      __builtin_bit_cast(bf16x8, a), __builtin_bit_cast(bf16x8, b), c, 0, 0, 0);
}
DEV void async16(void* lds_uniform, const void* gptr) {
  __builtin_amdgcn_global_load_lds(
      (const __attribute__((address_space(1))) void*)gptr,
      (__attribute__((address_space(3))) void*)lds_uniform, 16, 0, 0);
}

// ---------------- prep: casts ----------------

__global__ void cast2_bf4(const float4* __restrict__ srcA, short4* __restrict__ dstA,
                          const float4* __restrict__ srcB, short4* __restrict__ dstB,
                          long n4each) {
  long i = (long)blockIdx.x * blockDim.x + threadIdx.x;
  long stride = (long)gridDim.x * blockDim.x;
  for (; i < 2 * n4each; i += stride) {
    const float4* s; short4* d; long j;
    if (i < n4each) { s = srcA; d = dstA; j = i; }
    else { s = srcB; d = dstB; j = i - n4each; }
    float4 v = s[j];
    short4 o; o.x = f2bf(v.x); o.y = f2bf(v.y); o.z = f2bf(v.z); o.w = f2bf(v.w);
    d[j] = o;
  }
}

__global__ void cast_hl4(const float4* __restrict__ src, short4* __restrict__ dhi,
                         short4* __restrict__ dlo, long n4) {
  long i = (long)blockIdx.x * blockDim.x + threadIdx.x;
  long stride = (long)gridDim.x * blockDim.x;
  for (; i < n4; i += stride) {
    float4 v = src[i];
    short4 h, l;
    h.x = f2bf(v.x); l.x = f2bf(v.x - bf2f(h.x));
    h.y = f2bf(v.y); l.y = f2bf(v.y - bf2f(h.y));
    h.z = f2bf(v.z); l.z = f2bf(v.z - bf2f(h.z));
    h.w = f2bf(v.w); l.w = f2bf(v.w - bf2f(h.w));
    dhi[i] = h; dlo[i] = l;
  }
}

// src (K,N) f32 -> dst_hi/lo (Npad,K) bf16 (rows >= N zero)
__launch_bounds__(256)
__global__ void transpose_cast_hl(const float* __restrict__ src, short* __restrict__ dhi,
                                  short* __restrict__ dlo, int K, int N) {
  __shared__ float tile[64][65];
  int k0 = blockIdx.x * 64, n0 = blockIdx.y * 64;
  for (int i = threadIdx.x; i < 4096; i += 256) {
    int r = i >> 6, c = i & 63;
    tile[r][c] = (n0 + c < N) ? src[(size_t)(k0 + r) * N + n0 + c] : 0.f;
  }
  __syncthreads();
  for (int i = threadIdx.x; i < 4096; i += 256) {
    int r = i >> 6, c = i & 63;
    float v = tile[c][r];
    short h = f2bf(v);
    dhi[(size_t)(n0 + r) * K + k0 + c] = h;
    dlo[(size_t)(n0 + r) * K + k0 + c] = f2bf(v - bf2f(h));
  }
}

// ---------------- LayerNorm variants ----------------

__launch_bounds__(256)
__global__ void ln_hl(const float* __restrict__ in, int ldi, int N,
                      const float* __restrict__ w, const float* __restrict__ b,
                      short* __restrict__ ohi, short* __restrict__ olo, int ldo) {
  const int row = blockIdx.x * 4 + (threadIdx.x >> 6);
  const int lane = threadIdx.x & 63;
  const float* r = in + (size_t)row * ldi;
  float s = 0.f, s2 = 0.f;
  for (int i = lane; i < N; i += 64) { float v = r[i]; s += v; s2 += v * v; }
#pragma unroll
  for (int off = 32; off >= 1; off >>= 1) { s += __shfl_xor(s, off); s2 += __shfl_xor(s2, off); }
  float mean = s / N, var = s2 / N - mean * mean;
  float rstd = rsqrtf(var + 1e-5f);
  for (int i = lane; i < N; i += 64) {
    float y = (r[i] - mean) * rstd * w[i];
    if (b) y += b[i];
    short h = f2bf(y);
    ohi[(size_t)row * ldo + i] = h;
    olo[(size_t)row * ldo + i] = f2bf(y - bf2f(h));
  }
}

__launch_bounds__(256)
__global__ void ln_bf_f32(const float* __restrict__ in,
                          const float* __restrict__ w,
                          short* __restrict__ obf, float* __restrict__ of) {
  const int row = blockIdx.x * 4 + (threadIdx.x >> 6);
  const int lane = threadIdx.x & 63;
  const float* r = in + (size_t)row * 768;
  float s = 0.f, s2 = 0.f;
  for (int i = lane; i < 768; i += 64) { float v = r[i]; s += v; s2 += v * v; }
#pragma unroll
  for (int off = 32; off >= 1; off >>= 1) { s += __shfl_xor(s, off); s2 += __shfl_xor(s2, off); }
  float mean = s / 768.f, var = s2 / 768.f - mean * mean;
  float rstd = rsqrtf(var + 1e-5f);
  for (int i = lane; i < 768; i += 64) {
    float y = (r[i] - mean) * rstd * w[i];
    obf[(size_t)row * 768 + i] = f2bf(y);
    of[(size_t)row * 768 + i] = y;
  }
}

// ---------------- split-precision GEMM ----------------

template<int RESID>
__launch_bounds__(256)
__global__ void gemm3(const short* __restrict__ Ahi, const short* __restrict__ Alo, int lda,
                      const short* __restrict__ Bhi, const short* __restrict__ Blo, int ldb,
                      float* __restrict__ Cf, int ldc, const float* __restrict__ resid,
                      int M, int N, int K) {
  __shared__ __align__(16) short AsH[4096], AsL[4096], BsH[4096], BsL[4096];
  const int tid = threadIdx.x;
  const int m0 = blockIdx.y * 128, n0 = blockIdx.x * 128;
  const int wave = tid >> 6, lane = tid & 63;
  const int wm = (wave >> 1) * 64, wn = (wave & 1) * 64;
  const int lr = lane & 15, lk = (lane >> 4) * 8, rb = (lane >> 4) * 4;
  const floatx4 fz = {0.f, 0.f, 0.f, 0.f};
  floatx4 acc[4][4];
#pragma unroll
  for (int i = 0; i < 4; i++)
#pragma unroll
    for (int j = 0; j < 4; j++) acc[i][j] = fz;
  const size_t rowA = (size_t)(m0 + (tid >> 2)) * lda + (tid & 3) * 8;
  const size_t rowB = (size_t)(n0 + (tid >> 2)) * ldb + (tid & 3) * 8;
  const size_t a64 = (size_t)64 * lda, b64 = (size_t)64 * ldb;
  short* AsHW = AsH + wave * 512; short* AsLW = AsL + wave * 512;
  short* BsHW = BsH + wave * 512; short* BsLW = BsL + wave * 512;
  for (int k0 = 0; k0 < K; k0 += 32) {
    async16(AsHW, Ahi + rowA + k0);        async16(AsHW + 2048, Ahi + rowA + a64 + k0);
    async16(AsLW, Alo + rowA + k0);        async16(AsLW + 2048, Alo + rowA + a64 + k0);
    async16(BsHW, Bhi + rowB + k0);        async16(BsHW + 2048, Bhi + rowB + b64 + k0);
    async16(BsLW, Blo + rowB + k0);        async16(BsLW + 2048, Blo + rowB + b64 + k0);
    __syncthreads();
    short8 ah[4], al[4], bh[4], bl[4];
#pragma unroll
    for (int i = 0; i < 4; i++) {
      ah[i] = *(const short8*)&AsH[(wm + i * 16 + lr) * 32 + lk];
      al[i] = *(const short8*)&AsL[(wm + i * 16 + lr) * 32 + lk];
    }
#pragma unroll
    for (int j = 0; j < 4; j++) {
      bh[j] = *(const short8*)&BsH[(wn + j * 16 + lr) * 32 + lk];
      bl[j] = *(const short8*)&BsL[(wn + j * 16 + lr) * 32 + lk];
    }
#pragma unroll
    for (int i = 0; i < 4; i++)
#pragma unroll
      for (int j = 0; j < 4; j++) {
        acc[i][j] = mfma16(ah[i], bh[j], acc[i][j]);
        acc[i][j] = mfma16(ah[i], bl[j], acc[i][j]);
        acc[i][j] = mfma16(al[i], bh[j], acc[i][j]);
      }
    __syncthreads();
  }
#pragma unroll
  for (int i = 0; i < 4; i++) {
    int row = m0 + wm + i * 16 + rb;
#pragma unroll
    for (int j = 0; j < 4; j++) {
      int col = n0 + wn + j * 16 + lr;
      if (col < N) {
#pragma unroll
        for (int r = 0; r < 4; r++) {
          int rr = row + r;
          if (rr < M) {
            float v = acc[i][j][r];
            if (RESID) v += resid[(size_t)rr * ldc + col];
            Cf[(size_t)rr * ldc + col] = v;
          }
        }
      }
    }
  }
}

// ---------------- plain bf16 GEMM for MoE ----------------

template<int ACT, int BETA, int RESID>
__launch_bounds__(256)
__global__ void gemm1(const short* __restrict__ A, int lda,
                      const short* __restrict__ Bt, int ldb,
                      float* __restrict__ Cf, short* __restrict__ Cb, int ldc,
                      const float* __restrict__ resid,
                      int M, int N, int K) {
  __shared__ __align__(16) short As[4096], Bs[4096];
  const int tid = threadIdx.x;
  const int m0 = blockIdx.y * 128, n0 = blockIdx.x * 128;
  const int wave = tid >> 6, lane = tid & 63;
  const int wm = (wave >> 1) * 64, wn = (wave & 1) * 64;
  const int lr = lane & 15, lk = (lane >> 4) * 8, rb = (lane >> 4) * 4;
  const floatx4 fz = {0.f, 0.f, 0.f, 0.f};
  floatx4 acc[4][4];
#pragma unroll
  for (int i = 0; i < 4; i++)
#pragma unroll
    for (int j = 0; j < 4; j++) acc[i][j] = fz;
  const short* Ag = A + (size_t)(m0 + (tid >> 2)) * lda + (tid & 3) * 8;
  const short* Bg = Bt + (size_t)(n0 + (tid >> 2)) * ldb + (tid & 3) * 8;
  short* AsW = As + wave * 512; short* BsW = Bs + wave * 512;
  const size_t a64 = (size_t)64 * lda, b64 = (size_t)64 * ldb;
  for (int k0 = 0; k0 < K; k0 += 32) {
    async16(AsW, Ag + k0);  async16(AsW + 2048, Ag + a64 + k0);
    async16(BsW, Bg + k0);  async16(BsW + 2048, Bg + b64 + k0);
    __syncthreads();
    short8 af[4], bfr[4];
#pragma unroll
    for (int i = 0; i < 4; i++) af[i] = *(const short8*)&As[(wm + i * 16 + lr) * 32 + lk];
#pragma unroll
    for (int j = 0; j < 4; j++) bfr[j] = *(const short8*)&Bs[(wn + j * 16 + lr) * 32 + lk];
#pragma unroll
    for (int i = 0; i < 4; i++)
#pragma unroll
      for (int j = 0; j < 4; j++) acc[i][j] = mfma16(af[i], bfr[j], acc[i][j]);
    __syncthreads();
  }
#pragma unroll
  for (int i = 0; i < 4; i++) {
    int row = m0 + wm + i * 16 + rb;
#pragma unroll
    for (int j = 0; j < 4; j++) {
      int col = n0 + wn + j * 16 + lr;
      if (col < N) {
#pragma unroll
        for (int r = 0; r < 4; r++) {
          int rr = row + r;
          if (rr < M) {
            float v = acc[i][j][r];
            if (RESID) v += resid[(size_t)rr * ldc + col];
            if (BETA) v += Cf[(size_t)rr * ldc + col];
            if (ACT == 1) v = gelu_f(v);
            if (Cf) Cf[(size_t)rr * ldc + col] = v;
            if (Cb) Cb[(size_t)rr * ldc + col] = f2bf(v);
          }
        }
      }
    }
  }
}

// ---------------- RoPE builders (hi/lo planes) ----------------

__global__ void build_q_hl(const float* __restrict__ Qf, short* __restrict__ qh,
                           short* __restrict__ ql) {
  int id = blockIdx.x * blockDim.x + threadIdx.x;
  if (id >= 4096 * 12) return;
  int token = id / 12, h = id - token * 12;
  int s = token & 1023, b = token >> 10;
  const float* q = Qf + (size_t)token * 768 + h * 64;
  size_t base = ((size_t)(b * 12 + h) * 1024 + s) * 64;
  float vals[64];
#pragma unroll
  for (int d = 0; d < 32; d++) vals[d] = q[d];
#pragma unroll
  for (int i = 0; i < 16; i++) {
    float fi = powf(10000.f, -(float)(2 * i) / 64.f);
    float sn, cs; sincosf((float)s * fi, &sn, &cs);
    vals[32 + i] = q[32 + i] * cs - q[48 + i] * sn;
    vals[48 + i] = q[48 + i] * cs + q[32 + i] * sn;
  }
#pragma unroll
  for (int d = 0; d < 64; d++) {
    short hh = f2bf(vals[d]);
    qh[base + d] = hh;
    ql[base + d] = f2bf(vals[d] - bf2f(hh));
  }
}

__global__ void build_k_hl(const float* __restrict__ KVf, const float* __restrict__ ckv,
                           short* __restrict__ kh, short* __restrict__ kl) {
  int id = blockIdx.x * blockDim.x + threadIdx.x;
  if (id >= 4096 * 12) return;
  int token = id / 12, h = id - token * 12;
  int s = token & 1023, b = token >> 10;
  const float* kv = KVf + (size_t)token * 1152 + h * 96;
  size_t kb = ((size_t)(b * 12 + h) * 1024 + s) * 64;
  float kvals[64];
#pragma unroll
  for (int d = 0; d < 32; d++) kvals[d] = kv[d];
  const float* kr = ckv + (size_t)token * 544 + 512;
#pragma unroll
  for (int i = 0; i < 16; i++) {
    float fi = powf(10000.f, -(float)(2 * i) / 64.f);
    float sn, cs; sincosf((float)s * fi, &sn, &cs);
    kvals[32 + i] = kr[i] * cs - kr[16 + i] * sn;
    kvals[48 + i] = kr[16 + i] * cs + kr[i] * sn;
  }
#pragma unroll
  for (int d = 0; d < 64; d++) {
    short hh = f2bf(kvals[d]);
    kh[kb + d] = hh;
    kl[kb + d] = f2bf(kvals[d] - bf2f(hh));
  }
}

// V transpose through LDS: KVf (token-major, dims 32..96 of the 96-blk per head)
// -> vtH/vtL (bh, d, s). Coalesced both ways.
__launch_bounds__(256)
__global__ void build_vt_hl(const float* __restrict__ KVf,
                            short* __restrict__ vth, short* __restrict__ vtl) {
  __shared__ float tile[64][65];
  const int s0 = blockIdx.x * 64, bh = blockIdx.y;
  const int b = bh / 12, h = bh - b * 12;
  for (int i = threadIdx.x; i < 4096; i += 256) {
    int tl = i >> 6, d = i & 63;
    int token = b * 1024 + s0 + tl;
    tile[tl][d] = KVf[(size_t)token * 1152 + h * 96 + 32 + d];
  }
  __syncthreads();
  for (int i = threadIdx.x; i < 4096; i += 256) {
    int d = i >> 6, sl = i & 63;
    float v = tile[sl][d];
    short hh = f2bf(v);
    size_t idx = (size_t)bh * 65536 + (size_t)d * 1024 + s0 + sl;
    vth[idx] = hh;
    vtl[idx] = f2bf(v - bf2f(hh));
  }
}

// ---------------- flash attention, split precision ----------------

__launch_bounds__(256)
__global__ void attn3(const short* __restrict__ qbh, const short* __restrict__ qbl,
                      const short* __restrict__ kbh, const short* __restrict__ kbl,
                      const short* __restrict__ vth, const short* __restrict__ vtl,
                      short* __restrict__ obh, short* __restrict__ obl) {
  const int qt = blockIdx.x, bh = blockIdx.y;
  const int b = bh / 12, h = bh - b * 12;
  const short* Qh = qbh + (size_t)bh * 65536;
  const short* Ql = qbl + (size_t)bh * 65536;
  const short* Kh = kbh + (size_t)bh * 65536;
  const short* Kl = kbl + (size_t)bh * 65536;
  const short* Vh = vth + (size_t)bh * 65536;
  const short* Vl = vtl + (size_t)bh * 65536;
  __shared__ __align__(16) short KsH[4096], KsL[4096], VsH[4096], VsL[4096], PsH[4096], PsL[4096];
  const int tid = threadIdx.x, wave = tid >> 6, lane = tid & 63;
  const int lr = lane & 15, q4 = lane >> 4, lk = (lane >> 4) * 8;
  const int qrow0 = qt * 64 + wave * 16;
  short8 qfh[2], qfl[2];
  qfh[0] = *(const short8*)&Qh[(size_t)(qrow0 + lr) * 64 + lk];
  qfh[1] = *(const short8*)&Qh[(size_t)(qrow0 + lr) * 64 + 32 + lk];
  qfl[0] = *(const short8*)&Ql[(size_t)(qrow0 + lr) * 64 + lk];
  qfl[1] = *(const short8*)&Ql[(size_t)(qrow0 + lr) * 64 + 32 + lk];
  const floatx4 fz = {0.f, 0.f, 0.f, 0.f};
  floatx4 oacc[4];
#pragma unroll
  for (int t = 0; t < 4; t++) oacc[t] = fz;
  float m_i[4], l_i[4];
#pragma unroll
  for (int r = 0; r < 4; r++) { m_i[r] = -__builtin_inff(); l_i[r] = 0.f; }
  const int srow = tid >> 3, soff = (tid & 7) * 8;
  short* KsHW = KsH + wave * 512; short* KsLW = KsL + wave * 512;
  short* VsHW = VsH + wave * 512; short* VsLW = VsL + wave * 512;
  short* myPh = PsH + wave * 1024; short* myPl = PsL + wave * 1024;
  for (int kt = 0; kt <= qt; kt++) {
    __syncthreads();
    size_t krow = (size_t)(kt * 64 + srow) * 64 + soff;
    size_t vrow = (size_t)srow * 1024 + kt * 64 + soff;
    async16(KsHW, Kh + krow);        async16(KsHW + 2048, Kh + krow + 32 * 64);
    async16(KsLW, Kl + krow);        async16(KsLW + 2048, Kl + krow + 32 * 64);
    async16(VsHW, Vh + vrow);        async16(VsHW + 2048, Vh + vrow + 32 * 1024);
    async16(VsLW, Vl + vrow);        async16(VsLW + 2048, Vl + vrow + 32 * 1024);
    __syncthreads();
    floatx4 sacc[4];
#pragma unroll
    for (int j = 0; j < 4; j++) sacc[j] = fz;
#pragma unroll
    for (int j = 0; j < 4; j++) {
      short8 kh0 = *(const short8*)&KsH[(j * 16 + lr) * 64 + lk];
      short8 kh1 = *(const short8*)&KsH[(j * 16 + lr) * 64 + 32 + lk];
      short8 kl0 = *(const short8*)&KsL[(j * 16 + lr) * 64 + lk];
      short8 kl1 = *(const short8*)&KsL[(j * 16 + lr) * 64 + 32 + lk];
      sacc[j] = mfma16(qfh[0], kh0, sacc[j]);
      sacc[j] = mfma16(qfh[1], kh1, sacc[j]);
      sacc[j] = mfma16(qfh[0], kl0, sacc[j]);
      sacc[j] = mfma16(qfh[1], kl1, sacc[j]);
      sacc[j] = mfma16(qfl[0], kh0, sacc[j]);
      sacc[j] = mfma16(qfl[1], kh1, sacc[j]);
    }
    float pv[4][4], mrow[4];
#pragma unroll
    for (int r = 0; r < 4; r++) mrow[r] = -__builtin_inff();
    const bool diag = (kt == qt);
#pragma unroll
    for (int j = 0; j < 4; j++)
#pragma unroll
      for (int r = 0; r < 4; r++) {
        float v = sacc[j][r] * 0.125f;
        if (diag) {
          int qg = qrow0 + q4 * 4 + r;
          int kg = kt * 64 + j * 16 + lr;
          if (kg > qg) v = -__builtin_inff();
        }
        pv[j][r] = v;
        mrow[r] = fmaxf(mrow[r], v);
      }
#pragma unroll
    for (int r = 0; r < 4; r++)
#pragma unroll
      for (int off = 1; off < 16; off <<= 1) mrow[r] = fmaxf(mrow[r], __shfl_xor(mrow[r], off));
    float alpha[4], rsum[4];
#pragma unroll
    for (int r = 0; r < 4; r++) {
      float nm = fmaxf(m_i[r], mrow[r]);
      alpha[r] = __expf(m_i[r] - nm);
      m_i[r] = nm; rsum[r] = 0.f;
    }
#pragma unroll
    for (int j = 0; j < 4; j++)
#pragma unroll
      for (int r = 0; r < 4; r++) {
        float pe = __expf(pv[j][r] - m_i[r]);
        pv[j][r] = pe; rsum[r] += pe;
      }
#pragma unroll
    for (int r = 0; r < 4; r++) {
#pragma unroll
      for (int off = 1; off < 16; off <<= 1) rsum[r] += __shfl_xor(rsum[r], off);
      l_i[r] = l_i[r] * alpha[r] + rsum[r];
    }
#pragma unroll
    for (int t = 0; t < 4; t++)
#pragma unroll
      for (int r = 0; r < 4; r++) oacc[t][r] *= alpha[r];
#pragma unroll
    for (int j = 0; j < 4; j++)
#pragma unroll
      for (int r = 0; r < 4; r++) {
        float p = pv[j][r];
        short hh = f2bf(p);
        myPh[(q4 * 4 + r) * 64 + j * 16 + lr] = hh;
        myPl[(q4 * 4 + r) * 64 + j * 16 + lr] = f2bf(p - bf2f(hh));
      }
    __asm__ volatile("s_waitcnt lgkmcnt(0)" ::: "memory");
#pragma unroll
    for (int c = 0; c < 2; c++) {
      short8 ph = *(const short8*)&myPh[lr * 64 + c * 32 + lk];
      short8 pl = *(const short8*)&myPl[lr * 64 + c * 32 + lk];
#pragma unroll
      for (int t = 0; t < 4; t++) {
        short8 vh = *(const short8*)&VsH[(t * 16 + lr) * 64 + c * 32 + lk];
        short8 vl = *(const short8*)&VsL[(t * 16 + lr) * 64 + c * 32 + lk];
        oacc[t] = mfma16(ph, vh, oacc[t]);
        oacc[t] = mfma16(ph, vl, oacc[t]);
        oacc[t] = mfma16(pl, vh, oacc[t]);
      }
    }
  }
#pragma unroll
  for (int t = 0; t < 4; t++)
#pragma unroll
    for (int r = 0; r < 4; r++) {
      int s = qrow0 + q4 * 4 + r;
      int token = b * 1024 + s;
      float ov = oacc[t][r] / l_i[r];
      short hh = f2bf(ov);
      size_t idx = (size_t)token * 768 + h * 64 + t * 16 + lr;
      obh[idx] = hh;
      obl[idx] = f2bf(ov - bf2f(hh));
    }
}

// ---------------- routing: score (no atomics) + list compaction ----------------

__launch_bounds__(256)
__global__ void route_score(const float* __restrict__ h2f, const float* __restrict__ cent,
                            const float* __restrict__ rbias,
                            int* __restrict__ topexp, float* __restrict__ gates) {
  const int token = blockIdx.x * 4 + (threadIdx.x >> 6);
  const int lane = threadIdx.x & 63;
  const float* hv = h2f + (size_t)token * 768;
  float hreg[12];
#pragma unroll
  for (int ii = 0; ii < 12; ii++) hreg[ii] = hv[lane + 64 * ii];
  float raw[8];
#pragma unroll
  for (int e = 0; e < 8; e++) {
    const float* cv = cent + e * 768;
    float p = 0.f;
#pragma unroll
    for (int ii = 0; ii < 12; ii++) p += hreg[ii] * cv[lane + 64 * ii];
#pragma unroll
    for (int off = 32; off >= 1; off >>= 1) p += __shfl_xor(p, off);
    raw[e] = p;
  }
  if (lane == 0) {
    float b0 = -__builtin_inff(); int i1 = 0;
#pragma unroll
    for (int e = 0; e < 8; e++) { float be = raw[e] + rbias[e]; if (be > b0) { b0 = be; i1 = e; } }
    float b1 = -__builtin_inff(); int i2 = 0;
#pragma unroll
    for (int e = 0; e < 8; e++) {
      if (e == i1) continue;
      float be = raw[e] + rbias[e];
      if (be > b1) { b1 = be; i2 = e; }
    }
    float w1 = 1.f / (1.f + expf(-raw[i1]));
    float w2 = 1.f / (1.f + expf(-raw[i2]));
    float wsum = w1 + w2 + 1e-9f;
    topexp[token] = i1;        gates[token] = w1 / wsum;
    topexp[4096 + token] = i2; gates[4096 + token] = w2 / wsum;
  }
}

// 8 blocks (one per expert). Ballot-compact the 8192 (rank,token) slots.
__launch_bounds__(256)
__global__ void build_lists(const int* __restrict__ topexp,
                            int* __restrict__ counts, int* __restrict__ lists) {
  const int e = blockIdx.x;
  __shared__ int wave_off[4];
  const int wave = threadIdx.x >> 6, lane = threadIdx.x & 63;
  int total = 0;
  for (int c0 = 0; c0 < 8192; c0 += 256) {
    int slot = c0 + threadIdx.x;
    bool m = (topexp[slot] == e);
    unsigned long long bal = __ballot(m);
    int wcnt = __popcll(bal);
    int lpre = __popcll(bal & ((1ull << lane) - 1ull));
    if (lane == 0) wave_off[wave] = wcnt;
    __syncthreads();
    int woff = 0;
#pragma unroll
    for (int w = 0; w < 4; w++) if (w < wave) woff += wave_off[w];
    int chunk_total = wave_off[0] + wave_off[1] + wave_off[2] + wave_off[3];
    if (m) lists[e * 4096 + total + woff + lpre] = slot;  // slot == rank*4096+token
    total += chunk_total;
    __syncthreads();
  }
  if (threadIdx.x == 0) counts[e] = total;
}

// ---------------- per-expert grouped GEMMs ----------------

__launch_bounds__(256)
__global__ void expert_fc(const short* __restrict__ h2bf, const short* __restrict__ wfc,
                          const int* __restrict__ elist, const int* __restrict__ ecnt,
                          short* __restrict__ act) {
  const int cnt = *ecnt;
  const int m0 = blockIdx.y * 128;
  if (m0 >= cnt) return;
  const int n0 = blockIdx.x * 128;
  __shared__ __align__(16) short As[4096], Bs[4096];
  __shared__ int slots[128];
  const int tid = threadIdx.x;
  if (tid < 128) slots[tid] = elist[m0 + tid];
  __syncthreads();
  const int tokA0 = slots[tid >> 2] & 4095;
  const int tokA1 = slots[64 + (tid >> 2)] & 4095;
  const int wave = tid >> 6, lane = tid & 63;
  const int wm = (wave >> 1) * 64, wn = (wave & 1) * 64;
  const int lr = lane & 15, lk = (lane >> 4) * 8, rb = (lane >> 4) * 4;
  const floatx4 fz = {0.f, 0.f, 0.f, 0.f};
  floatx4 acc[4][4];
#pragma unroll
  for (int i = 0; i < 4; i++)
#pragma unroll
    for (int j = 0; j < 4; j++) acc[i][j] = fz;
  const short* Ag0 = h2bf + (size_t)tokA0 * 768 + (tid & 3) * 8;
  const short* Ag1 = h2bf + (size_t)tokA1 * 768 + (tid & 3) * 8;
  const short* Bg = wfc + (size_t)(n0 + (tid >> 2)) * 768 + (tid & 3) * 8;
  short* AsW = As + wave * 512; short* BsW = Bs + wave * 512;
  for (int k0 = 0; k0 < 768; k0 += 32) {
    async16(AsW, Ag0 + k0);  async16(AsW + 2048, Ag1 + k0);
    async16(BsW, Bg + k0);   async16(BsW + 2048, Bg + (size_t)64 * 768 + k0);
    __syncthreads();
    short8 af[4], bfr[4];
#pragma unroll
    for (int i = 0; i < 4; i++) af[i] = *(const short8*)&As[(wm + i * 16 + lr) * 32 + lk];
#pragma unroll
    for (int j = 0; j < 4; j++) bfr[j] = *(const short8*)&Bs[(wn + j * 16 + lr) * 32 + lk];
#pragma unroll
    for (int i = 0; i < 4; i++)
#pragma unroll
      for (int j = 0; j < 4; j++) acc[i][j] = mfma16(af[i], bfr[j], acc[i][j]);
    __syncthreads();
  }
#pragma unroll
  for (int i = 0; i < 4; i++) {
    int lrow = wm + i * 16 + rb;
#pragma unroll
    for (int j = 0; j < 4; j++) {
      int col = n0 + wn + j * 16 + lr;
#pragma unroll
      for (int r = 0; r < 4; r++) {
        if (m0 + lrow + r < cnt)
          act[(size_t)(m0 + lrow + r) * 3072 + col] = f2bf(gelu_f(acc[i][j][r]));
      }
    }
  }
}

__launch_bounds__(256)
__global__ void expert_proj(const short* __restrict__ act, const short* __restrict__ wproj,
                            const int* __restrict__ elist, const int* __restrict__ ecnt,
                            const float* __restrict__ gates, float* __restrict__ out) {
  const int cnt = *ecnt;
  const int m0 = blockIdx.y * 128;
  if (m0 >= cnt) return;
  const int n0 = blockIdx.x * 128;
  __shared__ __align__(16) short As[4096], Bs[4096];
  __shared__ int slots[128];
  const int tid = threadIdx.x;
  if (tid < 128) slots[tid] = elist[m0 + tid];
  __syncthreads();
  const int wave = tid >> 6, lane = tid & 63;
  const int wm = (wave >> 1) * 64, wn = (wave & 1) * 64;
  const int lr = lane & 15, lk = (lane >> 4) * 8, rb = (lane >> 4) * 4;
  const floatx4 fz = {0.f, 0.f, 0.f, 0.f};
  floatx4 acc[4][4];
#pragma unroll
  for (int i = 0; i < 4; i++)
#pragma unroll
    for (int j = 0; j < 4; j++) acc[i][j] = fz;
  const short* Ag = act + (size_t)(m0 + (tid >> 2)) * 3072 + (tid & 3) * 8;
  const short* Bg = wproj + (size_t)(n0 + (tid >> 2)) * 3072 + (tid & 3) * 8;
  short* AsW = As + wave * 512; short* BsW = Bs + wave * 512;
  for (int k0 = 0; k0 < 3072; k0 += 32) {
    async16(AsW, Ag + k0);  async16(AsW + 2048, Ag + (size_t)64 * 3072 + k0);
    async16(BsW, Bg + k0);  async16(BsW + 2048, Bg + (size_t)64 * 3072 + k0);
    __syncthreads();
    short8 af[4], bfr[4];
#pragma unroll
    for (int i = 0; i < 4; i++) af[i] = *(const short8*)&As[(wm + i * 16 + lr) * 32 + lk];
#pragma unroll
    for (int j = 0; j < 4; j++) bfr[j] = *(const short8*)&Bs[(wn + j * 16 + lr) * 32 + lk];
#pragma unroll
    for (int i = 0; i < 4; i++)
#pragma unroll
      for (int j = 0; j < 4; j++) acc[i][j] = mfma16(af[i], bfr[j], acc[i][j]);
    __syncthreads();
  }
#pragma unroll
  for (int i = 0; i < 4; i++) {
    int lrow = wm + i * 16 + rb;
#pragma unroll
    for (int j = 0; j < 4; j++) {
      int col = n0 + wn + j * 16 + lr;
#pragma unroll
      for (int r = 0; r < 4; r++) {
        if (m0 + lrow + r < cnt) {
          int slot = slots[lrow + r];
          int token = slot & 4095;
          atomicAdd(&out[(size_t)token * 768 + col], gates[slot] * acc[i][j][r]);
        }
      }
    }
  }
}

__global__ void bad_kernel(float* out) { out[threadIdx.x] = 1e30f; }

// ---------------- launch ----------------

extern "C" void kernel_launch(void* const* d_in, const int* in_sizes, int n_in,
                              void* d_out, int out_size, void* d_ws, size_t ws_size,
                              hipStream_t stream) {
  const float* x = (const float*)d_in[0];
  const float* ln1_w = (const float*)d_in[1];
  const float* ln2_w = (const float*)d_in[2];
  const float* W_dq = (const float*)d_in[3];
  const float* W_uq = (const float*)d_in[4];
  const float* q_ln_w = (const float*)d_in[5];
  const float* q_ln_b = (const float*)d_in[6];
  const float* W_dkv = (const float*)d_in[7];
  const float* W_ukv = (const float*)d_in[8];
  const float* kv_ln_w = (const float*)d_in[9];
  const float* kv_ln_b = (const float*)d_in[10];
  const float* W_o = (const float*)d_in[11];
  const float* s_fc = (const float*)d_in[12];
  const float* s_proj = (const float*)d_in[13];
  const float* e_fc = (const float*)d_in[14];
  const float* e_proj = (const float*)d_in[15];
  const float* cent = (const float*)d_in[16];
  const float* rbias = (const float*)d_in[17];
  float* out = (float*)d_out;

  char* base = (char*)d_ws;
  size_t off = 0;
  auto take = [&](size_t bytes) -> char* {
    char* r = base + off;
    off = (off + bytes + 255) & ~(size_t)255;
    return r;
  };
  // persistent
  short* WdqH  = (short*)take(589824);  short* WdqL  = (short*)take(589824);
  short* WuqH  = (short*)take(589824);  short* WuqL  = (short*)take(589824);
  short* WdkvH = (short*)take(983040);  short* WdkvL = (short*)take(983040);
  short* WukvH = (short*)take(1179648); short* WukvL = (short*)take(1179648);
  short* WoH   = (short*)take(1179648); short* WoL   = (short*)take(1179648);
  float* x2    = (float*)take(12582912);
  float* gates = (float*)take(32768);
  int*   counts= (int*)take(32);
  int*   lists = (int*)take(131072);
  int*   topexp= (int*)take(32768);
  // pool with overlays
  const size_t PLANE = 6291456;  // 4096*768*2 bytes
  char* pA = take(2 * PLANE);
  char* pB = take(2 * PLANE);
  char* pC = take(2 * PLANE);
  char* pD = take(2 * PLANE);
  char* pE = take(18874368);
  char* pF = take(8912896);
  size_t used = off;
  if (used > ws_size) { bad_kernel<<<1, 256, 0, stream>>>(out); return; }

  short* hH    = (short*)pA;             short* hL    = (short*)(pA + PLANE);
  short* kvlH  = (short*)pA;             short* kvlL  = (short*)(pA + 4194304);
  short* kbH   = (short*)pA;             short* kbL   = (short*)(pA + PLANE);
  float* cqpre = (float*)pB;
  short* cqH   = (short*)(pB + PLANE);   short* cqL   = (short*)(pB + PLANE + 3145728);
  short* vtH   = (short*)pB;             short* vtL   = (short*)(pB + PLANE);
  short* wbufB = (short*)pB;
  float* Qf    = (float*)pC;
  short* obH   = (short*)pC;             short* obL   = (short*)(pC + PLANE);
  short* h2bf  = (short*)pC;             short* wbufA = (short*)(pC + PLANE);
  short* qbH   = (short*)pD;             short* qbL   = (short*)(pD + PLANE);
  float* h2f   = (float*)pD;
  float* KVf   = (float*)pE;
  short* actb  = (short*)pE;             // 25.2 MB spans pE+pF
  float* ckv   = (float*)pF;

  // weight prep (hi/lo)
  cast_hl4<<<576, 256, 0, stream>>>((const float4*)W_o, (short4*)WoH, (short4*)WoL, 147456);
  transpose_cast_hl<<<dim3(12, 6), 256, 0, stream>>>(W_dq, WdqH, WdqL, 768, 384);
  transpose_cast_hl<<<dim3(6, 12), 256, 0, stream>>>(W_uq, WuqH, WuqL, 384, 768);
  transpose_cast_hl<<<dim3(12, 10), 256, 0, stream>>>(W_dkv, WdkvH, WdkvL, 768, 544);
  transpose_cast_hl<<<dim3(8, 18), 256, 0, stream>>>(W_ukv, WukvH, WukvL, 512, 1152);

  // phase A: pre-routing path in split precision
  ln_hl<<<1024, 256, 0, stream>>>(x, 768, 768, ln1_w, nullptr, hH, hL, 768);
  gemm3<0><<<dim3(3, 32), 256, 0, stream>>>(hH, hL, 768, WdqH, WdqL, 768, cqpre, 384, nullptr, 4096, 384, 768);
  ln_hl<<<1024, 256, 0, stream>>>(cqpre, 384, 384, q_ln_w, q_ln_b, cqH, cqL, 384);
  gemm3<0><<<dim3(6, 32), 256, 0, stream>>>(cqH, cqL, 384, WuqH, WuqL, 384, Qf, 768, nullptr, 4096, 768, 384);
  build_q_hl<<<192, 256, 0, stream>>>(Qf, qbH, qbL);
  gemm3<0><<<dim3(5, 32), 256, 0, stream>>>(hH, hL, 768, WdkvH, WdkvL, 768, ckv, 544, nullptr, 4096, 544, 768);
  ln_hl<<<1024, 256, 0, stream>>>(ckv, 544, 512, kv_ln_w, kv_ln_b, kvlH, kvlL, 512);
  gemm3<0><<<dim3(9, 32), 256, 0, stream>>>(kvlH, kvlL, 512, WukvH, WukvL, 512, KVf, 1152, nullptr, 4096, 1152, 512);
  build_k_hl<<<192, 256, 0, stream>>>(KVf, ckv, kbH, kbL);
  build_vt_hl<<<dim3(16, 48), 256, 0, stream>>>(KVf, vtH, vtL);
  attn3<<<dim3(16, 48), 256, 0, stream>>>(qbH, qbL, kbH, kbL, vtH, vtL, obH, obL);
  gemm3<1><<<dim3(6, 32), 256, 0, stream>>>(obH, obL, 768, WoH, WoL, 768, x2, 768, x, 4096, 768, 768);

  // phase B: LN2, routing (atomic-free), MoE (plain bf16)
  ln_bf_f32<<<1024, 256, 0, stream>>>(x2, ln2_w, h2bf, h2f);
  route_score<<<1024, 256, 0, stream>>>(h2f, cent, rbias, topexp, gates);
  build_lists<<<8, 256, 0, stream>>>(topexp, counts, lists);

  // shared expert 0: out = x2 + proj(gelu(fc(h2)))
  cast2_bf4<<<2048, 256, 0, stream>>>((const float4*)s_fc, (short4*)wbufA,
                                      (const float4*)s_proj, (short4*)wbufB, 589824);
  gemm1<1, 0, 0><<<dim3(24, 32), 256, 0, stream>>>(h2bf, 768, wbufA, 768, nullptr, actb, 3072, nullptr, 4096, 3072, 768);
  gemm1<0, 0, 1><<<dim3(6, 32), 256, 0, stream>>>(actb, 3072, wbufB, 3072, out, nullptr, 768, x2, 4096, 768, 3072);
  // shared expert 1: out += proj(gelu(fc(h2)))
  cast2_bf4<<<2048, 256, 0, stream>>>((const float4*)(s_fc + (size_t)3072 * 768), (short4*)wbufA,
                                      (const float4*)(s_proj + (size_t)768 * 3072), (short4*)wbufB, 589824);
  gemm1<1, 0, 0><<<dim3(24, 32), 256, 0, stream>>>(h2bf, 768, wbufA, 768, nullptr, actb, 3072, nullptr, 4096, 3072, 768);
  gemm1<0, 1, 0><<<dim3(6, 32), 256, 0, stream>>>(actb, 3072, wbufB, 3072, out, nullptr, 768, nullptr, 4096, 768, 3072);

  // routed experts, one at a time (act buffer reused; scatter via atomicAdd into out)
  for (int e = 0; e < 8; e++) {
    cast2_bf4<<<2048, 256, 0, stream>>>((const float4*)(e_fc + (size_t)e * 3072 * 768), (short4*)wbufA,
                                        (const float4*)(e_proj + (size_t)e * 768 * 3072), (short4*)wbufB, 589824);
    expert_fc<<<dim3(24, 32), 256, 0, stream>>>(h2bf, wbufA, lists + e * 4096, counts + e, actb);
    expert_proj<<<dim3(6, 32), 256, 0, stream>>>(actb, wbufB, lists + e * 4096, counts + e, gates, out);
  }
}

// Round 4
// 1098.948 us; speedup vs baseline: 1.7435x; 1.6126x over previous
//
#include <hip/hip_runtime.h>
#include <math.h>

// MLA + MoE block for gfx950. R4:
// - attn: XOR bank-swizzle on K/V staging, padded P (stride 72), paired q-tiles for balance
// - GEMMs: chunk-swizzled LDS (kills 8-way ds_read_b128 conflicts of the m97 layout)
// - fused launches: dq+dkv concat GEMM, fused LNs, concat shared experts (N=6144 fc,
//   split-k-4 atomic proj), z=4 batched routed experts. 65 -> 26 launches.

#define DEV __device__ __forceinline__

typedef __attribute__((ext_vector_type(8))) short short8;
typedef __attribute__((ext_vector_type(8))) __bf16 bf16x8;
typedef __attribute__((ext_vector_type(4))) float floatx4;

DEV short f2bf(float f) {
  union { float f; unsigned u; } v; v.f = f;
  unsigned r = v.u + 0x7fffu + ((v.u >> 16) & 1u);
  return (short)(r >> 16);
}
DEV float bf2f(short s) {
  union { float f; unsigned u; } v; v.u = ((unsigned)(unsigned short)s) << 16;
  return v.f;
}
DEV float gelu_f(float v) { return 0.5f * v * (1.0f + erff(v * 0.70710678118654752f)); }

DEV floatx4 mfma16(short8 a, short8 b, floatx4 c) {
  return __builtin_amdgcn_mfma_f32_16x16x32_bf16(
      __builtin_bit_cast(bf16x8, a), __builtin_bit_cast(bf16x8, b), c, 0, 0, 0);
}
DEV void async16(void* lds_uniform, const void* gptr) {
  __builtin_amdgcn_global_load_lds(
      (const __attribute__((address_space(1))) void*)gptr,
      (__attribute__((address_space(3))) void*)lds_uniform, 16, 0, 0);
}

// ---------------- prep: casts ----------------

__global__ void cast2_bf4(const float4* __restrict__ srcA, short4* __restrict__ dstA,
                          const float4* __restrict__ srcB, short4* __restrict__ dstB,
                          long n4each) {
  long i = (long)blockIdx.x * blockDim.x + threadIdx.x;
  long stride = (long)gridDim.x * blockDim.x;
  for (; i < 2 * n4each; i += stride) {
    const float4* s; short4* d; long j;
    if (i < n4each) { s = srcA; d = dstA; j = i; }
    else { s = srcB; d = dstB; j = i - n4each; }
    float4 v = s[j];
    short4 o; o.x = f2bf(v.x); o.y = f2bf(v.y); o.z = f2bf(v.z); o.w = f2bf(v.w);
    d[j] = o;
  }
}

// shared-expert weights: sfcCat = linear cast of s_fc (6144x768);
// sprojCat (768x6144): cols 0..3071 from proj0, 3072..6143 from proj1
__global__ void cast_shared(const float4* __restrict__ sfc4, const float4* __restrict__ sproj4,
                            short4* __restrict__ fcCat4, short4* __restrict__ projCat4) {
  long i = (long)blockIdx.x * 256 + threadIdx.x;
  float4 v;
  if (i < 1179648) {
    v = sfc4[i];
    short4 o; o.x = f2bf(v.x); o.y = f2bf(v.y); o.z = f2bf(v.z); o.w = f2bf(v.w);
    fcCat4[i] = o;
  } else {
    long j = i - 1179648;
    long d = j / 1536, k4 = j - d * 1536;
    v = (k4 < 768) ? sproj4[d * 768 + k4] : sproj4[589824 + d * 768 + (k4 - 768)];
    short4 o; o.x = f2bf(v.x); o.y = f2bf(v.y); o.z = f2bf(v.z); o.w = f2bf(v.w);
    projCat4[j] = o;
  }
}

__global__ void cast_hl4(const float4* __restrict__ src, short4* __restrict__ dhi,
                         short4* __restrict__ dlo, long n4) {
  long i = (long)blockIdx.x * blockDim.x + threadIdx.x;
  long stride = (long)gridDim.x * blockDim.x;
  for (; i < n4; i += stride) {
    float4 v = src[i];
    short4 h, l;
    h.x = f2bf(v.x); l.x = f2bf(v.x - bf2f(h.x));
    h.y = f2bf(v.y); l.y = f2bf(v.y - bf2f(h.y));
    h.z = f2bf(v.z); l.z = f2bf(v.z - bf2f(h.z));
    h.w = f2bf(v.w); l.w = f2bf(v.w - bf2f(h.w));
    dhi[i] = h; dlo[i] = l;
  }
}

// src (K,N) f32 -> dst_hi/lo (Nlocal_pad,K) bf16, rows >= N zero
__launch_bounds__(256)
__global__ void transpose_cast_hl(const float* __restrict__ src, short* __restrict__ dhi,
                                  short* __restrict__ dlo, int K, int N) {
  __shared__ float tile[64][65];
  int k0 = blockIdx.x * 64, n0 = blockIdx.y * 64;
  for (int i = threadIdx.x; i < 4096; i += 256) {
    int r = i >> 6, c = i & 63;
    tile[r][c] = (n0 + c < N) ? src[(size_t)(k0 + r) * N + n0 + c] : 0.f;
  }
  __syncthreads();
  for (int i = threadIdx.x; i < 4096; i += 256) {
    int r = i >> 6, c = i & 63;
    float v = tile[c][r];
    short h = f2bf(v);
    dhi[(size_t)(n0 + r) * K + k0 + c] = h;
    dlo[(size_t)(n0 + r) * K + k0 + c] = f2bf(v - bf2f(h));
  }
}

// ---------------- LayerNorms ----------------

__launch_bounds__(256)
__global__ void ln_hl(const float* __restrict__ in, int ldi, int N,
                      const float* __restrict__ w, const float* __restrict__ b,
                      short* __restrict__ ohi, short* __restrict__ olo, int ldo) {
  const int row = blockIdx.x * 4 + (threadIdx.x >> 6);
  const int lane = threadIdx.x & 63;
  const float* r = in + (size_t)row * ldi;
  float s = 0.f, s2 = 0.f;
  for (int i = lane; i < N; i += 64) { float v = r[i]; s += v; s2 += v * v; }
#pragma unroll
  for (int off = 32; off >= 1; off >>= 1) { s += __shfl_xor(s, off); s2 += __shfl_xor(s2, off); }
  float mean = s / N, var = s2 / N - mean * mean;
  float rstd = rsqrtf(var + 1e-5f);
  for (int i = lane; i < N; i += 64) {
    float y = (r[i] - mean) * rstd * w[i];
    if (b) y += b[i];
    short h = f2bf(y);
    ohi[(size_t)row * ldo + i] = h;
    olo[(size_t)row * ldo + i] = f2bf(y - bf2f(h));
  }
}

// fused q-LN (rows 0..4095, N=384) + kv-LN (rows 4096..8191, N=512) over Ccat (ld 928)
__launch_bounds__(256)
__global__ void ln_qkv(const float* __restrict__ Ccat,
                       const float* __restrict__ qw, const float* __restrict__ qb,
                       const float* __restrict__ kw, const float* __restrict__ kb,
                       short* __restrict__ cqH, short* __restrict__ cqL,
                       short* __restrict__ kvH, short* __restrict__ kvL) {
  const int vrow = blockIdx.x * 4 + (threadIdx.x >> 6);
  const int lane = threadIdx.x & 63;
  const float* r; int N; const float* w; const float* b; short* oh; short* ol; int ldo; int row;
  if (vrow < 4096) {
    row = vrow; r = Ccat + (size_t)row * 928; N = 384; w = qw; b = qb; oh = cqH; ol = cqL; ldo = 384;
  } else {
    row = vrow - 4096; r = Ccat + (size_t)row * 928 + 384; N = 512; w = kw; b = kb; oh = kvH; ol = kvL; ldo = 512;
  }
  float s = 0.f, s2 = 0.f;
  for (int i = lane; i < N; i += 64) { float v = r[i]; s += v; s2 += v * v; }
#pragma unroll
  for (int off = 32; off >= 1; off >>= 1) { s += __shfl_xor(s, off); s2 += __shfl_xor(s2, off); }
  float mean = s / N, var = s2 / N - mean * mean;
  float rstd = rsqrtf(var + 1e-5f);
  for (int i = lane; i < N; i += 64) {
    float y = (r[i] - mean) * rstd * w[i] + b[i];
    short h = f2bf(y);
    oh[(size_t)row * ldo + i] = h;
    ol[(size_t)row * ldo + i] = f2bf(y - bf2f(h));
  }
}

// LN2: writes h2 (bf16 + f32) and initializes out = x2
__launch_bounds__(256)
__global__ void ln_bf_f32(const float* __restrict__ in, const float* __restrict__ w,
                          short* __restrict__ obf, float* __restrict__ of,
                          float* __restrict__ outInit) {
  const int row = blockIdx.x * 4 + (threadIdx.x >> 6);
  const int lane = threadIdx.x & 63;
  const float* r = in + (size_t)row * 768;
  float s = 0.f, s2 = 0.f;
  for (int i = lane; i < 768; i += 64) { float v = r[i]; s += v; s2 += v * v; }
#pragma unroll
  for (int off = 32; off >= 1; off >>= 1) { s += __shfl_xor(s, off); s2 += __shfl_xor(s2, off); }
  float mean = s / 768.f, var = s2 / 768.f - mean * mean;
  float rstd = rsqrtf(var + 1e-5f);
  for (int i = lane; i < 768; i += 64) {
    float xv = r[i];
    float y = (xv - mean) * rstd * w[i];
    obf[(size_t)row * 768 + i] = f2bf(y);
    of[(size_t)row * 768 + i] = y;
    outInit[(size_t)row * 768 + i] = xv;
  }
}

// ---------------- split-precision GEMM (chunk-swizzled LDS) ----------------

template<int RESID>
__launch_bounds__(256)
__global__ void gemm3(const short* __restrict__ Ahi, const short* __restrict__ Alo, int lda,
                      const short* __restrict__ Bhi, const short* __restrict__ Blo, int ldb,
                      float* __restrict__ Cf, int ldc, const float* __restrict__ resid,
                      int M, int N, int K) {
  __shared__ __align__(16) short AsH[4096], AsL[4096], BsH[4096], BsL[4096];
  const int tid = threadIdx.x;
  const int m0 = blockIdx.y * 128, n0 = blockIdx.x * 128;
  const int wave = tid >> 6, lane = tid & 63;
  const int wm = (wave >> 1) * 64, wn = (wave & 1) * 64;
  const int lr = lane & 15, rb = (lane >> 4) * 4;
  const int stg = ((tid & 3) ^ ((tid >> 3) & 3)) * 8;       // staged chunk swizzle
  const int lkx = (((lane >> 4) ^ ((lr >> 1) & 3))) * 8;    // matching read swizzle
  const floatx4 fz = {0.f, 0.f, 0.f, 0.f};
  floatx4 acc[4][4];
#pragma unroll
  for (int i = 0; i < 4; i++)
#pragma unroll
    for (int j = 0; j < 4; j++) acc[i][j] = fz;
  const size_t rowA = (size_t)(m0 + (tid >> 2)) * lda + stg;
  const size_t rowB = (size_t)(n0 + (tid >> 2)) * ldb + stg;
  const size_t a64 = (size_t)64 * lda, b64 = (size_t)64 * ldb;
  short* AsHW = AsH + wave * 512; short* AsLW = AsL + wave * 512;
  short* BsHW = BsH + wave * 512; short* BsLW = BsL + wave * 512;
  for (int k0 = 0; k0 < K; k0 += 32) {
    async16(AsHW, Ahi + rowA + k0);        async16(AsHW + 2048, Ahi + rowA + a64 + k0);
    async16(AsLW, Alo + rowA + k0);        async16(AsLW + 2048, Alo + rowA + a64 + k0);
    async16(BsHW, Bhi + rowB + k0);        async16(BsHW + 2048, Bhi + rowB + b64 + k0);
    async16(BsLW, Blo + rowB + k0);        async16(BsLW + 2048, Blo + rowB + b64 + k0);
    __syncthreads();
    short8 ah[4], al[4], bh[4], bl[4];
#pragma unroll
    for (int i = 0; i < 4; i++) {
      ah[i] = *(const short8*)&AsH[(wm + i * 16 + lr) * 32 + lkx];
      al[i] = *(const short8*)&AsL[(wm + i * 16 + lr) * 32 + lkx];
    }
#pragma unroll
    for (int j = 0; j < 4; j++) {
      bh[j] = *(const short8*)&BsH[(wn + j * 16 + lr) * 32 + lkx];
      bl[j] = *(const short8*)&BsL[(wn + j * 16 + lr) * 32 + lkx];
    }
#pragma unroll
    for (int i = 0; i < 4; i++)
#pragma unroll
      for (int j = 0; j < 4; j++) {
        acc[i][j] = mfma16(ah[i], bh[j], acc[i][j]);
        acc[i][j] = mfma16(ah[i], bl[j], acc[i][j]);
        acc[i][j] = mfma16(al[i], bh[j], acc[i][j]);
      }
    __syncthreads();
  }
#pragma unroll
  for (int i = 0; i < 4; i++) {
    int row = m0 + wm + i * 16 + rb;
#pragma unroll
    for (int j = 0; j < 4; j++) {
      int col = n0 + wn + j * 16 + lr;
      if (col < N) {
#pragma unroll
        for (int r = 0; r < 4; r++) {
          int rr = row + r;
          if (rr < M) {
            float v = acc[i][j][r];
            if (RESID) v += resid[(size_t)rr * ldc + col];
            Cf[(size_t)rr * ldc + col] = v;
          }
        }
      }
    }
  }
}

// ---------------- plain bf16 GEMM + gelu -> bf16 out (shared fc) ----------------

__launch_bounds__(256)
__global__ void gemm_fc(const short* __restrict__ A, int lda,
                        const short* __restrict__ Bt, int ldb,
                        short* __restrict__ Cb, int ldc, int K) {
  __shared__ __align__(16) short As[4096], Bs[4096];
  const int tid = threadIdx.x;
  const int m0 = blockIdx.y * 128, n0 = blockIdx.x * 128;
  const int wave = tid >> 6, lane = tid & 63;
  const int wm = (wave >> 1) * 64, wn = (wave & 1) * 64;
  const int lr = lane & 15, rb = (lane >> 4) * 4;
  const int stg = ((tid & 3) ^ ((tid >> 3) & 3)) * 8;
  const int lkx = (((lane >> 4) ^ ((lr >> 1) & 3))) * 8;
  const floatx4 fz = {0.f, 0.f, 0.f, 0.f};
  floatx4 acc[4][4];
#pragma unroll
  for (int i = 0; i < 4; i++)
#pragma unroll
    for (int j = 0; j < 4; j++) acc[i][j] = fz;
  const short* Ag = A + (size_t)(m0 + (tid >> 2)) * lda + stg;
  const short* Bg = Bt + (size_t)(n0 + (tid >> 2)) * ldb + stg;
  short* AsW = As + wave * 512; short* BsW = Bs + wave * 512;
  const size_t a64 = (size_t)64 * lda, b64 = (size_t)64 * ldb;
  for (int k0 = 0; k0 < K; k0 += 32) {
    async16(AsW, Ag + k0);  async16(AsW + 2048, Ag + a64 + k0);
    async16(BsW, Bg + k0);  async16(BsW + 2048, Bg + b64 + k0);
    __syncthreads();
    short8 af[4], bfr[4];
#pragma unroll
    for (int i = 0; i < 4; i++) af[i] = *(const short8*)&As[(wm + i * 16 + lr) * 32 + lkx];
#pragma unroll
    for (int j = 0; j < 4; j++) bfr[j] = *(const short8*)&Bs[(wn + j * 16 + lr) * 32 + lkx];
#pragma unroll
    for (int i = 0; i < 4; i++)
#pragma unroll
      for (int j = 0; j < 4; j++) acc[i][j] = mfma16(af[i], bfr[j], acc[i][j]);
    __syncthreads();
  }
#pragma unroll
  for (int i = 0; i < 4; i++) {
    int row = m0 + wm + i * 16 + rb;
#pragma unroll
    for (int j = 0; j < 4; j++) {
      int col = n0 + wn + j * 16 + lr;
#pragma unroll
      for (int r = 0; r < 4; r++)
        Cb[(size_t)(row + r) * ldc + col] = f2bf(gelu_f(acc[i][j][r]));
    }
  }
}

// ---------------- shared proj: split-k, atomic accumulate into out ----------------

__launch_bounds__(256)
__global__ void gemm_sk(const short* __restrict__ A, int lda,
                        const short* __restrict__ Bt, int ldb,
                        float* __restrict__ out, int ldc, int klen) {
  __shared__ __align__(16) short As[4096], Bs[4096];
  const int tid = threadIdx.x;
  const int m0 = blockIdx.y * 128, n0 = blockIdx.x * 128;
  const int koff = blockIdx.z * klen;
  const int wave = tid >> 6, lane = tid & 63;
  const int wm = (wave >> 1) * 64, wn = (wave & 1) * 64;
  const int lr = lane & 15, rb = (lane >> 4) * 4;
  const int stg = ((tid & 3) ^ ((tid >> 3) & 3)) * 8;
  const int lkx = (((lane >> 4) ^ ((lr >> 1) & 3))) * 8;
  const floatx4 fz = {0.f, 0.f, 0.f, 0.f};
  floatx4 acc[4][4];
#pragma unroll
  for (int i = 0; i < 4; i++)
#pragma unroll
    for (int j = 0; j < 4; j++) acc[i][j] = fz;
  const short* Ag = A + (size_t)(m0 + (tid >> 2)) * lda + koff + stg;
  const short* Bg = Bt + (size_t)(n0 + (tid >> 2)) * ldb + koff + stg;
  short* AsW = As + wave * 512; short* BsW = Bs + wave * 512;
  const size_t a64 = (size_t)64 * lda, b64 = (size_t)64 * ldb;
  for (int k0 = 0; k0 < klen; k0 += 32) {
    async16(AsW, Ag + k0);  async16(AsW + 2048, Ag + a64 + k0);
    async16(BsW, Bg + k0);  async16(BsW + 2048, Bg + b64 + k0);
    __syncthreads();
    short8 af[4], bfr[4];
#pragma unroll
    for (int i = 0; i < 4; i++) af[i] = *(const short8*)&As[(wm + i * 16 + lr) * 32 + lkx];
#pragma unroll
    for (int j = 0; j < 4; j++) bfr[j] = *(const short8*)&Bs[(wn + j * 16 + lr) * 32 + lkx];
#pragma unroll
    for (int i = 0; i < 4; i++)
#pragma unroll
      for (int j = 0; j < 4; j++) acc[i][j] = mfma16(af[i], bfr[j], acc[i][j]);
    __syncthreads();
  }
#pragma unroll
  for (int i = 0; i < 4; i++) {
    int row = m0 + wm + i * 16 + rb;
#pragma unroll
    for (int j = 0; j < 4; j++) {
      int col = n0 + wn + j * 16 + lr;
#pragma unroll
      for (int r = 0; r < 4; r++)
        atomicAdd(&out[(size_t)(row + r) * ldc + col], acc[i][j][r]);
    }
  }
}

// ---------------- RoPE builders (hi/lo) ----------------

__global__ void build_qk(const float* __restrict__ Qf, const float* __restrict__ KVf,
                         const float* __restrict__ Ccat,
                         short* __restrict__ qh, short* __restrict__ ql,
                         short* __restrict__ kh, short* __restrict__ kl) {
  int id = blockIdx.x * blockDim.x + threadIdx.x;
  if (id >= 4096 * 12) return;
  int token = id / 12, hh_ = id - token * 12;
  int s = token & 1023, b = token >> 10;
  size_t base = ((size_t)(b * 12 + hh_) * 1024 + s) * 64;
  float vals[64];
  if (blockIdx.y == 0) {
    const float* q = Qf + (size_t)token * 768 + hh_ * 64;
#pragma unroll
    for (int d = 0; d < 32; d++) vals[d] = q[d];
#pragma unroll
    for (int i = 0; i < 16; i++) {
      float fi = powf(10000.f, -(float)(2 * i) / 64.f);
      float sn, cs; sincosf((float)s * fi, &sn, &cs);
      vals[32 + i] = q[32 + i] * cs - q[48 + i] * sn;
      vals[48 + i] = q[48 + i] * cs + q[32 + i] * sn;
    }
#pragma unroll
    for (int d = 0; d < 64; d++) {
      short h = f2bf(vals[d]);
      qh[base + d] = h; ql[base + d] = f2bf(vals[d] - bf2f(h));
    }
  } else {
    const float* kv = KVf + (size_t)token * 1152 + hh_ * 96;
#pragma unroll
    for (int d = 0; d < 32; d++) vals[d] = kv[d];
    const float* kr = Ccat + (size_t)token * 928 + 896;
#pragma unroll
    for (int i = 0; i < 16; i++) {
      float fi = powf(10000.f, -(float)(2 * i) / 64.f);
      float sn, cs; sincosf((float)s * fi, &sn, &cs);
      vals[32 + i] = kr[i] * cs - kr[16 + i] * sn;
      vals[48 + i] = kr[16 + i] * cs + kr[i] * sn;
    }
#pragma unroll
    for (int d = 0; d < 64; d++) {
      short h = f2bf(vals[d]);
      kh[base + d] = h; kl[base + d] = f2bf(vals[d] - bf2f(h));
    }
  }
}

__launch_bounds__(256)
__global__ void build_vt_hl(const float* __restrict__ KVf,
                            short* __restrict__ vth, short* __restrict__ vtl) {
  __shared__ float tile[64][65];
  const int s0 = blockIdx.x * 64, bh = blockIdx.y;
  const int b = bh / 12, h = bh - b * 12;
  for (int i = threadIdx.x; i < 4096; i += 256) {
    int tl = i >> 6, d = i & 63;
    int token = b * 1024 + s0 + tl;
    tile[tl][d] = KVf[(size_t)token * 1152 + h * 96 + 32 + d];
  }
  __syncthreads();
  for (int i = threadIdx.x; i < 4096; i += 256) {
    int d = i >> 6, sl = i & 63;
    float v = tile[sl][d];
    short hh = f2bf(v);
    size_t idx = (size_t)bh * 65536 + (size_t)d * 1024 + s0 + sl;
    vth[idx] = hh;
    vtl[idx] = f2bf(v - bf2f(hh));
  }
}

// ---------------- flash attention (swizzled, padded P, paired q-tiles) ----------------

__launch_bounds__(256)
__global__ void attn3(const short* __restrict__ qbh, const short* __restrict__ qbl,
                      const short* __restrict__ kbh, const short* __restrict__ kbl,
                      const short* __restrict__ vth, const short* __restrict__ vtl,
                      short* __restrict__ obh, short* __restrict__ obl) {
  const int bh = blockIdx.y;
  const int b = bh / 12, h = bh - b * 12;
  const short* Qh = qbh + (size_t)bh * 65536;
  const short* Ql = qbl + (size_t)bh * 65536;
  const short* Kh = kbh + (size_t)bh * 65536;
  const short* Kl = kbl + (size_t)bh * 65536;
  const short* Vh = vth + (size_t)bh * 65536;
  const short* Vl = vtl + (size_t)bh * 65536;
  __shared__ __align__(16) short KsH[4096], KsL[4096], VsH[4096], VsL[4096];
  __shared__ __align__(16) short PsH[4608], PsL[4608];
  const int tid = threadIdx.x, wave = tid >> 6, lane = tid & 63;
  const int lr = lane & 15, q4 = lane >> 4, lk = (lane >> 4) * 8;
  const int sx0 = ((q4 ^ (lr & 7))) * 8;            // K/V read swizzle, chunk c=0
  const int sx1 = (((4 + q4) ^ (lr & 7))) * 8;      // chunk c=1
  const int soff_sw = (((tid & 7) ^ ((tid >> 3) & 7))) * 8;  // staging swizzle
  const int srow = tid >> 3;
  short* KsHW = KsH + wave * 512; short* KsLW = KsL + wave * 512;
  short* VsHW = VsH + wave * 512; short* VsLW = VsL + wave * 512;
  short* myPh = PsH + wave * 1152; short* myPl = PsL + wave * 1152;
  const floatx4 fz = {0.f, 0.f, 0.f, 0.f};
#pragma unroll
  for (int ph = 0; ph < 2; ph++) {
    const int qt = ph ? 15 - blockIdx.x : blockIdx.x;
    const int qrow0 = qt * 64 + wave * 16;
    short8 qfh[2], qfl[2];
    qfh[0] = *(const short8*)&Qh[(size_t)(qrow0 + lr) * 64 + lk];
    qfh[1] = *(const short8*)&Qh[(size_t)(qrow0 + lr) * 64 + 32 + lk];
    qfl[0] = *(const short8*)&Ql[(size_t)(qrow0 + lr) * 64 + lk];
    qfl[1] = *(const short8*)&Ql[(size_t)(qrow0 + lr) * 64 + 32 + lk];
    floatx4 oacc[4];
#pragma unroll
    for (int t = 0; t < 4; t++) oacc[t] = fz;
    float m_i[4], l_i[4];
#pragma unroll
    for (int r = 0; r < 4; r++) { m_i[r] = -__builtin_inff(); l_i[r] = 0.f; }
    for (int kt = 0; kt <= qt; kt++) {
      __syncthreads();
      size_t krow = (size_t)(kt * 64 + srow) * 64 + soff_sw;
      size_t vrow = (size_t)srow * 1024 + kt * 64 + soff_sw;
      async16(KsHW, Kh + krow);        async16(KsHW + 2048, Kh + krow + 32 * 64);
      async16(KsLW, Kl + krow);        async16(KsLW + 2048, Kl + krow + 32 * 64);
      async16(VsHW, Vh + vrow);        async16(VsHW + 2048, Vh + vrow + 32 * 1024);
      async16(VsLW, Vl + vrow);        async16(VsLW + 2048, Vl + vrow + 32 * 1024);
      __syncthreads();
      floatx4 sacc[4];
#pragma unroll
      for (int j = 0; j < 4; j++) sacc[j] = fz;
#pragma unroll
      for (int j = 0; j < 4; j++) {
        int rbase = (j * 16 + lr) * 64;
        short8 kh0 = *(const short8*)&KsH[rbase + sx0];
        short8 kh1 = *(const short8*)&KsH[rbase + sx1];
        short8 kl0 = *(const short8*)&KsL[rbase + sx0];
        short8 kl1 = *(const short8*)&KsL[rbase + sx1];
        sacc[j] = mfma16(qfh[0], kh0, sacc[j]);
        sacc[j] = mfma16(qfh[1], kh1, sacc[j]);
        sacc[j] = mfma16(qfh[0], kl0, sacc[j]);
        sacc[j] = mfma16(qfh[1], kl1, sacc[j]);
        sacc[j] = mfma16(qfl[0], kh0, sacc[j]);
        sacc[j] = mfma16(qfl[1], kh1, sacc[j]);
      }
      float pv[4][4], mrow[4];
#pragma unroll
      for (int r = 0; r < 4; r++) mrow[r] = -__builtin_inff();
      const bool diag = (kt == qt);
#pragma unroll
      for (int j = 0; j < 4; j++)
#pragma unroll
        for (int r = 0; r < 4; r++) {
          float v = sacc[j][r] * 0.125f;
          if (diag) {
            int qg = qrow0 + q4 * 4 + r;
            int kg = kt * 64 + j * 16 + lr;
            if (kg > qg) v = -__builtin_inff();
          }
          pv[j][r] = v;
          mrow[r] = fmaxf(mrow[r], v);
        }
#pragma unroll
      for (int r = 0; r < 4; r++)
#pragma unroll
        for (int off = 1; off < 16; off <<= 1) mrow[r] = fmaxf(mrow[r], __shfl_xor(mrow[r], off));
      float alpha[4], rsum[4];
#pragma unroll
      for (int r = 0; r < 4; r++) {
        float nm = fmaxf(m_i[r], mrow[r]);
        alpha[r] = __expf(m_i[r] - nm);
        m_i[r] = nm; rsum[r] = 0.f;
      }
#pragma unroll
      for (int j = 0; j < 4; j++)
#pragma unroll
        for (int r = 0; r < 4; r++) {
          float pe = __expf(pv[j][r] - m_i[r]);
          pv[j][r] = pe; rsum[r] += pe;
        }
#pragma unroll
      for (int r = 0; r < 4; r++) {
#pragma unroll
        for (int off = 1; off < 16; off <<= 1) rsum[r] += __shfl_xor(rsum[r], off);
        l_i[r] = l_i[r] * alpha[r] + rsum[r];
      }
#pragma unroll
      for (int t = 0; t < 4; t++)
#pragma unroll
        for (int r = 0; r < 4; r++) oacc[t][r] *= alpha[r];
#pragma unroll
      for (int j = 0; j < 4; j++)
#pragma unroll
        for (int r = 0; r < 4; r++) {
          float p = pv[j][r];
          short hh = f2bf(p);
          myPh[(q4 * 4 + r) * 72 + j * 16 + lr] = hh;
          myPl[(q4 * 4 + r) * 72 + j * 16 + lr] = f2bf(p - bf2f(hh));
        }
      __asm__ volatile("s_waitcnt lgkmcnt(0)" ::: "memory");
#pragma unroll
      for (int c = 0; c < 2; c++) {
        short8 ph_ = *(const short8*)&myPh[lr * 72 + c * 32 + lk];
        short8 pl_ = *(const short8*)&myPl[lr * 72 + c * 32 + lk];
        const int sxc = c ? sx1 : sx0;
#pragma unroll
        for (int t = 0; t < 4; t++) {
          int rbase = (t * 16 + lr) * 64;
          short8 vh = *(const short8*)&VsH[rbase + sxc];
          short8 vl = *(const short8*)&VsL[rbase + sxc];
          oacc[t] = mfma16(ph_, vh, oacc[t]);
          oacc[t] = mfma16(ph_, vl, oacc[t]);
          oacc[t] = mfma16(pl_, vh, oacc[t]);
        }
      }
    }
#pragma unroll
    for (int t = 0; t < 4; t++)
#pragma unroll
      for (int r = 0; r < 4; r++) {
        int s = qrow0 + q4 * 4 + r;
        int token = b * 1024 + s;
        float ov = oacc[t][r] / l_i[r];
        short hh = f2bf(ov);
        size_t idx = (size_t)token * 768 + h * 64 + t * 16 + lr;
        obh[idx] = hh;
        obl[idx] = f2bf(ov - bf2f(hh));
      }
  }
}

// ---------------- routing ----------------

__launch_bounds__(256)
__global__ void route_score(const float* __restrict__ h2f, const float* __restrict__ cent,
                            const float* __restrict__ rbias,
                            int* __restrict__ topexp, float* __restrict__ gates) {
  const int token = blockIdx.x * 4 + (threadIdx.x >> 6);
  const int lane = threadIdx.x & 63;
  const float* hv = h2f + (size_t)token * 768;
  float hreg[12];
#pragma unroll
  for (int ii = 0; ii < 12; ii++) hreg[ii] = hv[lane + 64 * ii];
  float raw[8];
#pragma unroll
  for (int e = 0; e < 8; e++) {
    const float* cv = cent + e * 768;
    float p = 0.f;
#pragma unroll
    for (int ii = 0; ii < 12; ii++) p += hreg[ii] * cv[lane + 64 * ii];
#pragma unroll
    for (int off = 32; off >= 1; off >>= 1) p += __shfl_xor(p, off);
    raw[e] = p;
  }
  if (lane == 0) {
    float b0 = -__builtin_inff(); int i1 = 0;
#pragma unroll
    for (int e = 0; e < 8; e++) { float be = raw[e] + rbias[e]; if (be > b0) { b0 = be; i1 = e; } }
    float b1 = -__builtin_inff(); int i2 = 0;
#pragma unroll
    for (int e = 0; e < 8; e++) {
      if (e == i1) continue;
      float be = raw[e] + rbias[e];
      if (be > b1) { b1 = be; i2 = e; }
    }
    float w1 = 1.f / (1.f + expf(-raw[i1]));
    float w2 = 1.f / (1.f + expf(-raw[i2]));
    float wsum = w1 + w2 + 1e-9f;
    topexp[token] = i1;        gates[token] = w1 / wsum;
    topexp[4096 + token] = i2; gates[4096 + token] = w2 / wsum;
  }
}

__launch_bounds__(256)
__global__ void build_lists(const int* __restrict__ topexp,
                            int* __restrict__ counts, int* __restrict__ lists) {
  const int e = blockIdx.x;
  __shared__ int wave_off[4];
  const int wave = threadIdx.x >> 6, lane = threadIdx.x & 63;
  int total = 0;
  for (int c0 = 0; c0 < 8192; c0 += 256) {
    int slot = c0 + threadIdx.x;
    bool m = (topexp[slot] == e);
    unsigned long long bal = __ballot(m);
    int wcnt = __popcll(bal);
    int lpre = __popcll(bal & ((1ull << lane) - 1ull));
    if (lane == 0) wave_off[wave] = wcnt;
    __syncthreads();
    int woff = 0;
#pragma unroll
    for (int w = 0; w < 4; w++) if (w < wave) woff += wave_off[w];
    int chunk_total = wave_off[0] + wave_off[1] + wave_off[2] + wave_off[3];
    if (m) lists[e * 4096 + total + woff + lpre] = slot;
    total += chunk_total;
    __syncthreads();
  }
  if (threadIdx.x == 0) counts[e] = total;
}

// ---------------- z-batched expert GEMMs ----------------

__launch_bounds__(256)
__global__ void expert_fc_z(const short* __restrict__ h2bf, const short* __restrict__ wfc,
                            const int* __restrict__ lists, const int* __restrict__ counts,
                            int ebase, short* __restrict__ act) {
  const int lz = blockIdx.z, e = ebase + lz;
  const int cnt = counts[e];
  const int m0 = blockIdx.y * 128;
  if (m0 >= cnt) return;
  int aoff = 0;
  for (int i = 0; i < lz; i++) aoff += counts[ebase + i];
  const int n0 = blockIdx.x * 128;
  __shared__ __align__(16) short As[4096], Bs[4096];
  __shared__ int slots[128];
  const int tid = threadIdx.x;
  if (tid < 128) slots[tid] = lists[e * 4096 + m0 + tid];
  __syncthreads();
  const int tokA0 = slots[tid >> 2] & 4095;
  const int tokA1 = slots[64 + (tid >> 2)] & 4095;
  const int wave = tid >> 6, lane = tid & 63;
  const int wm = (wave >> 1) * 64, wn = (wave & 1) * 64;
  const int lr = lane & 15, rb = (lane >> 4) * 4;
  const int stg = ((tid & 3) ^ ((tid >> 3) & 3)) * 8;
  const int lkx = (((lane >> 4) ^ ((lr >> 1) & 3))) * 8;
  const floatx4 fz = {0.f, 0.f, 0.f, 0.f};
  floatx4 acc[4][4];
#pragma unroll
  for (int i = 0; i < 4; i++)
#pragma unroll
    for (int j = 0; j < 4; j++) acc[i][j] = fz;
  const short* Ag0 = h2bf + (size_t)tokA0 * 768 + stg;
  const short* Ag1 = h2bf + (size_t)tokA1 * 768 + stg;
  const short* Bg = wfc + (size_t)lz * (3072 * 768) + (size_t)(n0 + (tid >> 2)) * 768 + stg;
  short* AsW = As + wave * 512; short* BsW = Bs + wave * 512;
  for (int k0 = 0; k0 < 768; k0 += 32) {
    async16(AsW, Ag0 + k0);  async16(AsW + 2048, Ag1 + k0);
    async16(BsW, Bg + k0);   async16(BsW + 2048, Bg + (size_t)64 * 768 + k0);
    __syncthreads();
    short8 af[4], bfr[4];
#pragma unroll
    for (int i = 0; i < 4; i++) af[i] = *(const short8*)&As[(wm + i * 16 + lr) * 32 + lkx];
#pragma unroll
    for (int j = 0; j < 4; j++) bfr[j] = *(const short8*)&Bs[(wn + j * 16 + lr) * 32 + lkx];
#pragma unroll
    for (int i = 0; i < 4; i++)
#pragma unroll
      for (int j = 0; j < 4; j++) acc[i][j] = mfma16(af[i], bfr[j], acc[i][j]);
    __syncthreads();
  }
#pragma unroll
  for (int i = 0; i < 4; i++) {
    int lrow = wm + i * 16 + rb;
#pragma unroll
    for (int j = 0; j < 4; j++) {
      int col = n0 + wn + j * 16 + lr;
#pragma unroll
      for (int r = 0; r < 4; r++) {
        if (m0 + lrow + r < cnt)
          act[(size_t)(aoff + m0 + lrow + r) * 3072 + col] = f2bf(gelu_f(acc[i][j][r]));
      }
    }
  }
}

__launch_bounds__(256)
__global__ void expert_proj_z(const short* __restrict__ act, const short* __restrict__ wproj,
                              const int* __restrict__ lists, const int* __restrict__ counts,
                              int ebase, const float* __restrict__ gates,
                              float* __restrict__ out) {
  const int lz = blockIdx.z >> 1, kh = blockIdx.z & 1, e = ebase + lz;
  const int cnt = counts[e];
  const int m0 = blockIdx.y * 128;
  if (m0 >= cnt) return;
  int aoff = 0;
  for (int i = 0; i < lz; i++) aoff += counts[ebase + i];
  const int koff = kh * 1536;
  const int n0 = blockIdx.x * 128;
  __shared__ __align__(16) short As[4096], Bs[4096];
  __shared__ int slots[128];
  const int tid = threadIdx.x;
  if (tid < 128) slots[tid] = lists[e * 4096 + m0 + tid];
  __syncthreads();
  const int wave = tid >> 6, lane = tid & 63;
  const int wm = (wave >> 1) * 64, wn = (wave & 1) * 64;
  const int lr = lane & 15, rb = (lane >> 4) * 4;
  const int stg = ((tid & 3) ^ ((tid >> 3) & 3)) * 8;
  const int lkx = (((lane >> 4) ^ ((lr >> 1) & 3))) * 8;
  const floatx4 fz = {0.f, 0.f, 0.f, 0.f};
  floatx4 acc[4][4];
#pragma unroll
  for (int i = 0; i < 4; i++)
#pragma unroll
    for (int j = 0; j < 4; j++) acc[i][j] = fz;
  const short* Ag = act + (size_t)(aoff + m0 + (tid >> 2)) * 3072 + koff + stg;
  const short* Bg = wproj + (size_t)lz * (768 * 3072) + (size_t)(n0 + (tid >> 2)) * 3072 + koff + stg;
  short* AsW = As + wave * 512; short* BsW = Bs + wave * 512;
  for (int k0 = 0; k0 < 1536; k0 += 32) {
    async16(AsW, Ag + k0);  async16(AsW + 2048, Ag + (size_t)64 * 3072 + k0);
    async16(BsW, Bg + k0);  async16(BsW + 2048, Bg + (size_t)64 * 3072 + k0);
    __syncthreads();
    short8 af[4], bfr[4];
#pragma unroll
    for (int i = 0; i < 4; i++) af[i] = *(const short8*)&As[(wm + i * 16 + lr) * 32 + lkx];
#pragma unroll
    for (int j = 0; j < 4; j++) bfr[j] = *(const short8*)&Bs[(wn + j * 16 + lr) * 32 + lkx];
#pragma unroll
    for (int i = 0; i < 4; i++)
#pragma unroll
      for (int j = 0; j < 4; j++) acc[i][j] = mfma16(af[i], bfr[j], acc[i][j]);
    __syncthreads();
  }
#pragma unroll
  for (int i = 0; i < 4; i++) {
    int lrow = wm + i * 16 + rb;
#pragma unroll
    for (int j = 0; j < 4; j++) {
      int col = n0 + wn + j * 16 + lr;
#pragma unroll
      for (int r = 0; r < 4; r++) {
        if (m0 + lrow + r < cnt) {
          int slot = slots[lrow + r];
          int token = slot & 4095;
          atomicAdd(&out[(size_t)token * 768 + col], gates[slot] * acc[i][j][r]);
        }
      }
    }
  }
}

__global__ void bad_kernel(float* out) { out[threadIdx.x] = 1e30f; }

// ---------------- launch ----------------

extern "C" void kernel_launch(void* const* d_in, const int* in_sizes, int n_in,
                              void* d_out, int out_size, void* d_ws, size_t ws_size,
                              hipStream_t stream) {
  const float* x = (const float*)d_in[0];
  const float* ln1_w = (const float*)d_in[1];
  const float* ln2_w = (const float*)d_in[2];
  const float* W_dq = (const float*)d_in[3];
  const float* W_uq = (const float*)d_in[4];
  const float* q_ln_w = (const float*)d_in[5];
  const float* q_ln_b = (const float*)d_in[6];
  const float* W_dkv = (const float*)d_in[7];
  const float* W_ukv = (const float*)d_in[8];
  const float* kv_ln_w = (const float*)d_in[9];
  const float* kv_ln_b = (const float*)d_in[10];
  const float* W_o = (const float*)d_in[11];
  const float* s_fc = (const float*)d_in[12];
  const float* s_proj = (const float*)d_in[13];
  const float* e_fc = (const float*)d_in[14];
  const float* e_proj = (const float*)d_in[15];
  const float* cent = (const float*)d_in[16];
  const float* rbias = (const float*)d_in[17];
  float* out = (float*)d_out;

  char* base = (char*)d_ws;
  size_t off = 0;
  auto take = [&](size_t bytes) -> char* {
    char* r = base + off;
    off = (off + bytes + 255) & ~(size_t)255;
    return r;
  };
  short* WcatH = (short*)take(1572864);  short* WcatL = (short*)take(1572864);
  short* WuqH  = (short*)take(589824);   short* WuqL  = (short*)take(589824);
  short* WukvH = (short*)take(1179648);  short* WukvL = (short*)take(1179648);
  short* WoH   = (short*)take(1179648);  short* WoL   = (short*)take(1179648);
  float* x2    = (float*)take(12582912);
  float* gates = (float*)take(32768);
  int*   counts= (int*)take(32);
  int*   lists = (int*)take(131072);
  int*   topexp= (int*)take(32768);
  const size_t PLANE = 6291456;
  char* pool = take(4 * 2 * PLANE);        // 50.33 MB, pA..pD contiguous
  char* R    = take(51118080);             // 50.33 MB + 128-row pad
  size_t used = off;
  if (used > ws_size) { bad_kernel<<<1, 256, 0, stream>>>(out); return; }
  char* pA = pool;
  char* pB = pool + 2 * PLANE;
  char* pC = pool + 4 * PLANE;
  char* pD = pool + 6 * PLANE;

  // phase A overlays
  short* hH   = (short*)pA;            short* hL   = (short*)(pA + PLANE);
  float* Ccat = (float*)R;                                   // 4096x928 f32 (15.2 MB)
  short* cqH  = (short*)pB;            short* cqL  = (short*)(pB + 3145728);
  short* kvlH = (short*)pD;            short* kvlL = (short*)(pD + 4194304);
  float* Qf   = (float*)pC;
  float* KVf  = (float*)(R + 15204352);                      // 4096x1152 f32 (18.9 MB)
  short* qbH  = (short*)pD;            short* qbL  = (short*)(pD + PLANE);
  short* kbH  = (short*)pA;            short* kbL  = (short*)(pA + PLANE);
  short* vtH  = (short*)pB;            short* vtL  = (short*)(pB + PLANE);
  short* obH  = (short*)pC;            short* obL  = (short*)(pC + PLANE);
  // phase B overlays
  short* h2bf    = (short*)(pD + PLANE);
  float* h2f     = (float*)pC;
  short* sfcCat  = (short*)pA;                               // 6144x768 bf16 (9.4 MB)
  short* sprojCat= (short*)(pA + 9437184);                   // 768x6144 bf16
  short* actCat  = (short*)R;                                // 4096x6144 bf16 (50.3 MB)
  short* efcHalf = (short*)pA;                               // 4x(3072x768) bf16 (18.9 MB)
  short* eprojHalf=(short*)(pA + 18874368);                  // 4x(768x3072) bf16
  short* eact    = (short*)R;                                // up to 8192+128 rows x 3072

  // ---- weight prep ----
  cast_hl4<<<576, 256, 0, stream>>>((const float4*)W_o, (short4*)WoH, (short4*)WoL, 147456);
  transpose_cast_hl<<<dim3(12, 6), 256, 0, stream>>>(W_dq, WcatH, WcatL, 768, 384);
  transpose_cast_hl<<<dim3(12, 10), 256, 0, stream>>>(W_dkv, WcatH + (size_t)384 * 768,
                                                      WcatL + (size_t)384 * 768, 768, 544);
  transpose_cast_hl<<<dim3(6, 12), 256, 0, stream>>>(W_uq, WuqH, WuqL, 384, 768);
  transpose_cast_hl<<<dim3(8, 18), 256, 0, stream>>>(W_ukv, WukvH, WukvL, 512, 1152);

  // ---- phase A ----
  ln_hl<<<1024, 256, 0, stream>>>(x, 768, 768, ln1_w, nullptr, hH, hL, 768);
  gemm3<0><<<dim3(8, 32), 256, 0, stream>>>(hH, hL, 768, WcatH, WcatL, 768, Ccat, 928, nullptr, 4096, 928, 768);
  ln_qkv<<<2048, 256, 0, stream>>>(Ccat, q_ln_w, q_ln_b, kv_ln_w, kv_ln_b, cqH, cqL, kvlH, kvlL);
  gemm3<0><<<dim3(6, 32), 256, 0, stream>>>(cqH, cqL, 384, WuqH, WuqL, 384, Qf, 768, nullptr, 4096, 768, 384);
  gemm3<0><<<dim3(9, 32), 256, 0, stream>>>(kvlH, kvlL, 512, WukvH, WukvL, 512, KVf, 1152, nullptr, 4096, 1152, 512);
  build_qk<<<dim3(192, 2), 256, 0, stream>>>(Qf, KVf, Ccat, qbH, qbL, kbH, kbL);
  build_vt_hl<<<dim3(16, 48), 256, 0, stream>>>(KVf, vtH, vtL);
  attn3<<<dim3(8, 48), 256, 0, stream>>>(qbH, qbL, kbH, kbL, vtH, vtL, obH, obL);
  gemm3<1><<<dim3(6, 32), 256, 0, stream>>>(obH, obL, 768, WoH, WoL, 768, x2, 768, x, 4096, 768, 768);

  // ---- phase B ----
  ln_bf_f32<<<1024, 256, 0, stream>>>(x2, ln2_w, h2bf, h2f, out);
  route_score<<<1024, 256, 0, stream>>>(h2f, cent, rbias, topexp, gates);
  build_lists<<<8, 256, 0, stream>>>(topexp, counts, lists);

  // shared experts (concat): fc -> gelu -> actCat ; proj split-k4 atomic into out
  cast_shared<<<9216, 256, 0, stream>>>((const float4*)s_fc, (const float4*)s_proj,
                                        (short4*)sfcCat, (short4*)sprojCat);
  gemm_fc<<<dim3(48, 32), 256, 0, stream>>>(h2bf, 768, sfcCat, 768, actCat, 6144, 768);
  gemm_sk<<<dim3(6, 32, 4), 256, 0, stream>>>(actCat, 6144, sprojCat, 6144, out, 768, 1536);

  // routed experts: two halves of 4, z-batched
  for (int h = 0; h < 2; h++) {
    cast2_bf4<<<2048, 256, 0, stream>>>(
        (const float4*)(e_fc + (size_t)h * 4 * 3072 * 768), (short4*)efcHalf,
        (const float4*)(e_proj + (size_t)h * 4 * 768 * 3072), (short4*)eprojHalf, 2359296);
    expert_fc_z<<<dim3(24, 32, 4), 256, 0, stream>>>(h2bf, efcHalf, lists, counts, h * 4, eact);
    expert_proj_z<<<dim3(6, 32, 8), 256, 0, stream>>>(eact, eprojHalf, lists, counts, h * 4, gates, out);
  }
}